// Round 15
// baseline (1163.470 us; speedup 1.0000x reference)
//
#include <hip/hip_runtime.h>
#include <hip/hip_bf16.h>
#include <cstdint>

using f32x4 = __attribute__((ext_vector_type(4))) float;
using s16x8 = __attribute__((ext_vector_type(8))) short;
using s16x4 = __attribute__((ext_vector_type(4))) short;

#define MFMA16(A,Bv,Cv) __builtin_amdgcn_mfma_f32_16x16x32_bf16((A),(Bv),(Cv),0,0,0)

__device__ __forceinline__ short f2bf(float f){
  __hip_bfloat16 h = __float2bfloat16(f);           // RNE; compiler fuses pairs to v_cvt_pk_bf16_f32
  union { __hip_bfloat16 h; short s; } u; u.h = h;
  return u.s;
}
__device__ __forceinline__ float bf2f(short s){
  union { unsigned u; float f; } v; v.u = ((unsigned)(unsigned short)s) << 16;
  return v.f;
}
// async global->LDS, 16B per lane; dest = uniform base + lane*16 (HW rule)
__device__ __forceinline__ void gload16(const short* g, short* l){
  __builtin_amdgcn_global_load_lds((const __attribute__((address_space(1))) unsigned int*)g,
                                   (__attribute__((address_space(3))) unsigned int*)l, 16, 0, 0);
}

static constexpr float SCALE_QK = 0.17677669529663687f; // 32^-0.5

// ---- workspace plan: k1/k2/k3 full-batch; k4/k5/k6 chunked (4 batches) ----
struct WS {
  short *wfrag, *wqkT, *wprojT, *pv, *winp, *pq, *pk, *pa, *pvT, *po;
};
static size_t ws_plan(char* base, WS* w) {
  size_t o = 0;
  auto take = [&](size_t bytes) -> short* {
    short* p = (short*)(base + o); o += (bytes + 255) & ~(size_t)255; return p;
  };
  short* wfrag = take((size_t)12*12*6*512*2);      // qkv weights in FRAGMENT order (884 KB)
  short* wqkT  = take((size_t)768*384*2);
  short* wproj = take((size_t)384*384*2);
  short* pv    = take((size_t)16*12*256*1568*2);   // full: 154 MB
  short* winp  = take((size_t)4096*384*2);
  short* pq    = take((size_t)16*12*256*32*2);
  short* pk    = take((size_t)16*12*256*32*2);
  short* pa    = take((size_t)16*12*256*256*2);    // full: 100 MB
  short* pvT   = take((size_t)4*12*256*1568*2);    // chunk: 38.5 MB
  short* po    = take((size_t)4*12544*384*2);      // chunk: 38.5 MB
  if (w) { w->wfrag=wfrag; w->wqkT=wqkT; w->wprojT=wproj; w->pv=pv; w->winp=winp;
           w->pq=pq; w->pk=pk; w->pa=pa; w->pvT=pvT; w->po=po; }
  return o;   // ~350 MB
}

// ---------------- k0: weight prep ----------------
// wfrag[hh][ks][half][lane][8]: half 0/1=q lo/hi-16-rows, 2/3=k, 4/5=v; lane=(q16<<4)|l15.
__global__ __launch_bounds__(256) void k0_prep(const float* __restrict__ wqkv,
    const float* __restrict__ wqk, const float* __restrict__ wproj,
    short* __restrict__ wfrag, short* __restrict__ wqkT, short* __restrict__ wprojT)
{
  int i = blockIdx.x * 256 + threadIdx.x;
  if (i < 442368) {
    int j = i & 7, lane = (i >> 3) & 63, half = (i >> 9) % 6, rest = i / 3072;
    int ks = rest % 12, hh = rest / 12;
    int q16 = lane >> 4, l15 = lane & 15;
    int row = (half >> 1)*384 + hh*32 + (half & 1)*16 + l15;
    int col = ks*32 + q16*8 + j;
    wfrag[i] = f2bf(wqkv[(size_t)col*1152 + row]);
    return;
  }
  i -= 442368;
  if (i < 768*384) { int nn = i / 384, kk = i % 384; wqkT[i] = f2bf(wqk[kk*768 + nn]); return; }
  i -= 768*384;
  if (i < 384*384) { int nn = i / 384, kk = i % 384; wprojT[i] = f2bf(wproj[kk*384 + nn]); }
}

// ---------------- k1: fused qkv GEMM + window attention + residual + LN/GELU ----------------
// (256,2) = no-spill operating point (5 experiments). wfrag = wave-contiguous 1KB weight loads.
// v-pass is a SINGLE K sweep (cv[4][2]): Wv loaded once (was twice under the old ksp split).
__global__ __launch_bounds__(256, 2) void k1_win_attn(
    const float* __restrict__ x, const short* __restrict__ wfrag,
    const float* __restrict__ lng, const float* __restrict__ lnb,
    short* __restrict__ pv, short* __restrict__ winpost)
{
  __shared__ short xb[52*392];   // rows 0..49 = x bf16 (ld 392); rows 50..51 alias win[384] floats
  __shared__ float rbuf[8];
  float* win = reinterpret_cast<float*>(&xb[50*392]);

  const int tid = threadIdx.x;
  const int w = tid >> 6;
  const int lane = tid & 63;
  const int l15 = lane & 15, q16 = lane >> 4;
  const int wl = blockIdx.x;             // global window (0..4095)
  const int bl = wl >> 8, n = wl & 255;  // batch, window idx

  {
    const float* xp = x + (size_t)wl * (50*384);
    for (int i = tid; i < 4800; i += 256) {
      float4 v = reinterpret_cast<const float4*>(xp)[i];
      int e = i * 4, t = e / 384, k = e % 384;
      short4 s4; s4.x = f2bf(v.x); s4.y = f2bf(v.y); s4.z = f2bf(v.z); s4.w = f2bf(v.w);
      *reinterpret_cast<short4*>(&xb[t*392 + k]) = s4;
    }
  }
  __syncthreads();

  for (int ih = 0; ih < 3; ++ih) {
    const int hh = w*3 + ih;

    // ---- fused q+k pass: Cq = Wq.x^T, Ck = Wk.x^T (shared x B-frags)
    f32x4 cq[2][4], ck[2][4];
#pragma unroll
    for (int mt=0; mt<2; ++mt)
#pragma unroll
      for (int nt=0; nt<4; ++nt) { cq[mt][nt]=f32x4{0.f,0.f,0.f,0.f}; ck[mt][nt]=f32x4{0.f,0.f,0.f,0.f}; }
    for (int ks = 0; ks < 12; ++ks) {
      const short* wfb = wfrag + ((size_t)(hh*12 + ks)*6)*512 + lane*8;
      s16x8 awq0 = *reinterpret_cast<const s16x8*>(wfb);
      s16x8 awq1 = *reinterpret_cast<const s16x8*>(wfb + 512);
      s16x8 awk0 = *reinterpret_cast<const s16x8*>(wfb + 1024);
      s16x8 awk1 = *reinterpret_cast<const s16x8*>(wfb + 1536);
#pragma unroll
      for (int nt=0; nt<4; ++nt) {
        int rr = nt*16 + l15; rr = rr > 51 ? 51 : rr;   // rows 50/51 garbage (win) — col-isolated
        s16x8 bx = *reinterpret_cast<const s16x8*>(&xb[rr*392 + ks*32 + q16*8]);
        cq[0][nt] = MFMA16(awq0, bx, cq[0][nt]);
        cq[1][nt] = MFMA16(awq1, bx, cq[1][nt]);
        ck[0][nt] = MFMA16(awk0, bx, ck[0][nt]);
        ck[1][nt] = MFMA16(awk1, bx, ck[1][nt]);
      }
    }
    // pack fragments in-register (k-map g1(q16,j) = (j>>2)*16 + q16*4 + (j&3)); fold scale into q
    s16x8 qf[4], kf[4];
#pragma unroll
    for (int nt=0; nt<4; ++nt)
#pragma unroll
      for (int j=0; j<8; ++j) {
        qf[nt][j] = f2bf(cq[j>>2][nt][j&3] * SCALE_QK);  // B-frag q[t=l15][dd=g1]
        kf[nt][j] = f2bf(ck[j>>2][nt][j&3]);             // A-frag k[s=l15][dd=g1] (nt = sti)
      }

    // ---- S^T per t-frag: 4 MFMA + no-max softmax (sum only) + pack unnormalized P
    s16x8 pf[4][2];
    float inv4[4];
#pragma unroll
    for (int nt=0; nt<4; ++nt) {
      f32x4 stc[4];
#pragma unroll
      for (int sti=0; sti<4; ++sti) {
        f32x4 z = {0.f,0.f,0.f,0.f};
        stc[sti] = MFMA16(kf[sti], qf[nt], z);
      }
      float sum = 0.f;
#pragma unroll
      for (int sti=0; sti<4; ++sti)
#pragma unroll
        for (int r=0;r<4;++r) {
          int s = sti*16 + q16*4 + r;
          float p = (s < 50) ? __expf(stc[sti][r]) : 0.f;   // garbage rows predicated off
          stc[sti][r] = p; sum += p;
        }
      sum += __shfl_xor(sum, 16);
      sum += __shfl_xor(sum, 32);
      inv4[nt] = 1.f / sum;
#pragma unroll
      for (int ksp=0; ksp<2; ++ksp)
#pragma unroll
        for (int j=0;j<8;++j)
          pf[nt][ksp][j] = f2bf(stc[ksp*2 + (j>>2)][j&3]);
    }

    // ---- v-pass: single K sweep, cv[4][2] (Wv loaded once)
    f32x4 cv[4][2];
#pragma unroll
    for (int sg=0; sg<4; ++sg) { cv[sg][0]=f32x4{0.f,0.f,0.f,0.f}; cv[sg][1]=f32x4{0.f,0.f,0.f,0.f}; }
    for (int ks=0; ks<12; ++ks) {
      const short* wfb = wfrag + ((size_t)(hh*12 + ks)*6)*512 + lane*8;
      s16x8 bw0 = *reinterpret_cast<const s16x8*>(wfb + 2048);
      s16x8 bw1 = *reinterpret_cast<const s16x8*>(wfb + 2560);
#pragma unroll
      for (int sg=0; sg<4; ++sg){
        int rr = sg*16 + l15; rr = rr > 51 ? 51 : rr;
        s16x8 ax = *reinterpret_cast<const s16x8*>(&xb[rr*392 + ks*32 + q16*8]);
        cv[sg][0] = MFMA16(ax, bw0, cv[sg][0]);
        cv[sg][1] = MFMA16(ax, bw1, cv[sg][1]);
      }
    }

    // ---- O^T = vT . P^T (K=64 over s); vf guarded s<50
    f32x4 ot[2][4];
#pragma unroll
    for (int mt=0; mt<2; ++mt)
#pragma unroll
      for (int nt=0; nt<4; ++nt) ot[mt][nt] = f32x4{0.f,0.f,0.f,0.f};
#pragma unroll
    for (int ksp=0; ksp<2; ++ksp)
#pragma unroll
      for (int mt=0; mt<2; ++mt) {
        s16x8 vf;
#pragma unroll
        for (int j=0;j<8;++j) {
          int s = ksp*32 + (j>>2)*16 + q16*4 + (j&3);
          vf[j] = (s < 50) ? f2bf(cv[ksp*2 + (j>>2)][mt][j&3]) : (short)0;
        }
#pragma unroll
        for (int nt=0; nt<4; ++nt) ot[mt][nt] = MFMA16(vf, pf[nt][ksp], ot[mt][nt]);
      }

    // ---- epilogue: apply deferred inv + residual + scatter
    short* pvb = pv + (((size_t)bl*12 + hh)*256 + n) * 1568;
#pragma unroll
    for (int nt=0; nt<4; ++nt) {
      int t = nt*16 + l15;
      if (t >= 1 && t < 50) {
#pragma unroll
        for (int mt=0; mt<2; ++mt) {
          short4 s4;
#pragma unroll
          for (int r=0;r<4;++r) {
            int dd = mt*16 + q16*4 + r;
            float val = ot[mt][nt][r] * inv4[nt] + bf2f(xb[t*392 + hh*32 + dd]);
            ((short*)&s4)[r] = f2bf(val);
          }
          *reinterpret_cast<short4*>(&pvb[(size_t)(t-1)*32 + mt*16 + q16*4]) = s4;
        }
      } else if (t == 0) {
#pragma unroll
        for (int mt=0; mt<2; ++mt)
#pragma unroll
          for (int r=0;r<4;++r) {
            int dd = mt*16 + q16*4 + r;
            win[hh*32 + dd] = ot[mt][nt][r] * inv4[nt] + bf2f(xb[hh*32 + dd]);
          }
      }
    }
  }

  __syncthreads();
  // ---- LayerNorm + exact GELU on window token
  float s1 = 0.f, s2 = 0.f;
  for (int c = tid; c < 384; c += 256) { float v = win[c]; s1 += v; s2 += v*v; }
#pragma unroll
  for (int o = 32; o >= 1; o >>= 1) { s1 += __shfl_xor(s1, o); s2 += __shfl_xor(s2, o); }
  if (lane == 0) { rbuf[w] = s1; rbuf[4+w] = s2; }
  __syncthreads();
  s1 = rbuf[0] + rbuf[1] + rbuf[2] + rbuf[3];
  s2 = rbuf[4] + rbuf[5] + rbuf[6] + rbuf[7];
  float mean = s1 * (1.f/384.f);
  float var  = s2 * (1.f/384.f) - mean*mean;
  float rstd = rsqrtf(var + 1e-5f);
  for (int c = tid; c < 384; c += 256) {
    float xn = (win[c] - mean) * rstd * lng[c] + lnb[c];
    float ge = 0.5f * xn * (1.f + erff(xn * 0.70710678118654752f));
    winpost[(size_t)wl*384 + c] = f2bf(ge);
  }
}

// ---------------- k2: pq/pk = win_post @ W_qk; SCALE_QK folded into pq (full batch) ----------------
__global__ __launch_bounds__(256) void k2_pqk(const short* __restrict__ winp,
    const short* __restrict__ wqkT, short* __restrict__ pq, short* __restrict__ pk)
{
  const int tid = threadIdx.x;
  const int w = tid >> 6, lane = tid & 63;
  const int l15 = lane & 15, q16 = lane >> 4;
  const int m0 = blockIdx.x * 64, n0 = blockIdx.y * 64;
  f32x4 acc[4];
#pragma unroll
  for (int nt=0; nt<4; ++nt) acc[nt] = f32x4{0.f,0.f,0.f,0.f};
  const int mrow = m0 + w*16 + l15;
  for (int ks2=0; ks2<12; ++ks2) {
    s16x8 a = *reinterpret_cast<const s16x8*>(winp + (size_t)mrow*384 + ks2*32 + q16*8);
#pragma unroll
    for (int nt=0; nt<4; ++nt) {
      s16x8 bf = *reinterpret_cast<const s16x8*>(wqkT + (size_t)(n0 + nt*16 + l15)*384 + ks2*32 + q16*8);
      acc[nt] = MFMA16(a, bf, acc[nt]);
    }
  }
#pragma unroll
  for (int nt=0; nt<4; ++nt)
#pragma unroll
    for (int r=0; r<4; ++r) {
      int m = m0 + w*16 + q16*4 + r;
      int bb = m >> 8, nn = m & 255;
      int c = n0 + nt*16 + l15;
      short* dst = (c >= 384) ? pk : pq;
      float v = acc[nt][r];
      if (c < 384) v *= SCALE_QK;        // fold scale into pq
      int hc = (c >= 384) ? (c - 384) : c;
      int hh = hc >> 5, dd = hc & 31;
      dst[(((size_t)bb*12 + hh)*256 + nn)*32 + dd] = f2bf(v);
    }
}

// ---------------- k3: pa = softmax(pq . pk^T) — 4x row-parallel (grid 192x4) ----------------
__global__ __launch_bounds__(256) void k3_pa(const short* __restrict__ pq,
    const short* __restrict__ pk, short* __restrict__ pa)
{
  __shared__ short ql[64*40];
  __shared__ short kl2[256*40];
  const int tid = threadIdx.x;
  const int w = tid >> 6, lane = tid & 63;
  const int l15 = lane & 15, q16 = lane >> 4;
  const int bh = blockIdx.x, by = blockIdx.y;
  const short* qs = pq + (size_t)bh * 8192;
  const short* ksp = pk + (size_t)bh * 8192;
  {
    int nn = tid >> 2, dd = (tid & 3) * 8;   // ql quarter: rows by*64..+64
    *reinterpret_cast<s16x8*>(&ql[nn*40 + dd]) =
        *reinterpret_cast<const s16x8*>(qs + (size_t)(by*64 + nn)*32 + dd);
  }
  for (int i = tid; i < 1024; i += 256) {
    int nn = i >> 2, dd = (i & 3) * 8;
    *reinterpret_cast<s16x8*>(&kl2[nn*40 + dd]) = *reinterpret_cast<const s16x8*>(ksp + i*8);
  }
  __syncthreads();
  s16x8 a = *reinterpret_cast<const s16x8*>(&ql[(w*16 + l15)*40 + q16*8]);
  f32x4 acc[16];
#pragma unroll
  for (int nt=0; nt<16; ++nt) {
    s16x8 bf = *reinterpret_cast<const s16x8*>(&kl2[(nt*16 + l15)*40 + q16*8]);
    f32x4 z = {0.f,0.f,0.f,0.f};
    acc[nt] = MFMA16(a, bf, z);
  }
#pragma unroll
  for (int r=0; r<4; ++r) {
    float sum = 0.f;
#pragma unroll
    for (int nt=0; nt<16; ++nt) { float p = __expf(acc[nt][r]); acc[nt][r] = p; sum += p; }
    sum += __shfl_xor(sum, 1); sum += __shfl_xor(sum, 2);
    sum += __shfl_xor(sum, 4); sum += __shfl_xor(sum, 8);
    float inv = 1.f / sum;
    int row = by*64 + w*16 + q16*4 + r;
    short* dst = pa + ((size_t)bh*256 + row) * 256;
#pragma unroll
    for (int nt=0; nt<16; ++nt) dst[nt*16 + l15] = f2bf(acc[nt][r] * inv);
  }
}

// ---------------- k4: transpose pv -> pvT, vectorized (64n x 32c tiles, short8 both ways) ----------------
__global__ __launch_bounds__(256) void k4_tr(const short* __restrict__ pv, short* __restrict__ pvT)
{
  __shared__ short tb[64*32];
  const int tid = threadIdx.x;
  const int bh = blockIdx.z;
  const int c0 = blockIdx.y * 32;
  const int n0 = blockIdx.x * 64;
  const short* src = pv + (size_t)bh * 256 * 1568;
  short* dst = pvT + (size_t)bh * 1568 * 256;

  {
    const int row = tid >> 2, oct = tid & 3;
    const int soct = oct ^ ((row >> 3) & 3);                  // swizzled 16B-chunk slot
    s16x8 v = *reinterpret_cast<const s16x8*>(&src[(size_t)(n0 + row)*1568 + c0 + oct*8]);
    *reinterpret_cast<s16x8*>(&tb[row*32 + soct*8]) = v;
  }
  __syncthreads();
  {
    const int c = tid >> 3, moct = tid & 7;                   // c 0..31, m-oct 0..7
    s16x8 o;
#pragma unroll
    for (int j = 0; j < 8; ++j) {
      int m = moct*8 + j;
      int soct = (c >> 3) ^ ((m >> 3) & 3);                   // inverse of the same involution
      o[j] = tb[m*32 + soct*8 + (c & 7)];
    }
    *reinterpret_cast<s16x8*>(&dst[(size_t)(c0 + c)*256 + n0 + moct*8]) = o;
  }
}

// ---------------- k5: po = pa @ pv + attn_x (residual from pv, coalesced); PIXEL-ORDER out ----------------
__global__ __launch_bounds__(256) void k5_po(const short* __restrict__ pa,
    const short* __restrict__ pv, const short* __restrict__ pvT, short* __restrict__ po)
{
  const int tid = threadIdx.x;
  const int w = tid >> 6, lane = tid & 63;
  const int l15 = lane & 15, q16 = lane >> 4;
  const int c0 = blockIdx.x * 112;
  const int m0 = blockIdx.y * 64;
  const int bh = blockIdx.z;
  const short* pab = pa + (size_t)bh * 256 * 256;
  const short* pvb = pvT + (size_t)bh * 1568 * 256;
  const short* pvs = pv + (size_t)bh * 256 * 1568;
  const int mrow = m0 + w*16;
  f32x4 acc[7];
#pragma unroll
  for (int nt=0; nt<7; ++nt) acc[nt] = f32x4{0.f,0.f,0.f,0.f};
  for (int ks2 = 0; ks2 < 8; ++ks2) {
    s16x8 a = *reinterpret_cast<const s16x8*>(pab + (size_t)(mrow + l15)*256 + ks2*32 + q16*8);
#pragma unroll
    for (int nt=0; nt<7; ++nt) {
      s16x8 bf = *reinterpret_cast<const s16x8*>(pvb + (size_t)(c0 + nt*16 + l15)*256 + ks2*32 + q16*8);
      acc[nt] = MFMA16(a, bf, acc[nt]);
    }
  }
  const int bl = bh / 12, hh = bh % 12;
#pragma unroll
  for (int nt=0; nt<7; ++nt)
#pragma unroll
    for (int r=0; r<4; ++r) {
      int nn = mrow + q16*4 + r;
      int col = c0 + nt*16 + l15;
      float val = acc[nt][r] + bf2f(pvs[(size_t)nn*1568 + col]);   // coalesced residual read
      int wp2 = col >> 5, dd = col & 31;
      int y = (nn >> 4)*7 + wp2/7, xx = (nn & 15)*7 + wp2%7;
      po[((size_t)bl*12544 + y*112 + xx)*384 + hh*32 + dd] = f2bf(val);
    }
}

// ---------------- k6: linear GEMM out = po_lin @ wprojT^T + bias (m97 structure + T2 swizzle) ----------------
__global__ __launch_bounds__(256) void k6_gemm(const short* __restrict__ A,
    const short* __restrict__ Bw, const float* __restrict__ bias,
    float* __restrict__ out, int b0)
{
  __shared__ short lA[2][128*64];
  __shared__ short lB[2][128*64];
  const int tid = threadIdx.x;
  const int w = tid >> 6, lane = tid & 63;
  const int l15 = lane & 15, q16 = lane >> 4;
  const int m0 = blockIdx.x * 128, n0 = blockIdx.y * 128;

  const int srow = lane >> 3;
  const int c16s = (lane & 7) ^ srow;
  const short* aSrc0 = A  + (size_t)(m0 + w*32 + srow)*384 + c16s*8;
  const short* bSrc0 = Bw + (size_t)(n0 + w*32 + srow)*384 + c16s*8;

  f32x4 acc[4][4];
#pragma unroll
  for (int mt=0; mt<4; ++mt)
#pragma unroll
    for (int nt=0; nt<4; ++nt) acc[mt][nt] = f32x4{0.f,0.f,0.f,0.f};

  const int wm = w >> 1, wn = w & 1;

#pragma unroll
  for (int j=0; j<4; ++j) {
    gload16(aSrc0 + j*8*384, &lA[0][(w*4 + j)*512]);
    gload16(bSrc0 + j*8*384, &lB[0][(w*4 + j)*512]);
  }
  __syncthreads();

  int cur = 0;
  for (int t = 0; t < 6; ++t) {
    if (t < 5) {
      const short* aS = aSrc0 + (t+1)*64;
      const short* bS = bSrc0 + (t+1)*64;
#pragma unroll
      for (int j=0; j<4; ++j) {
        gload16(aS + j*8*384, &lA[cur^1][(w*4 + j)*512]);
        gload16(bS + j*8*384, &lB[cur^1][(w*4 + j)*512]);
      }
    }
    const short* bufA = lA[cur];
    const short* bufB = lB[cur];
    s16x8 a[4][2], b[4][2];
#pragma unroll
    for (int mt=0; mt<4; ++mt) {
      int ra = wm*64 + mt*16 + l15;
#pragma unroll
      for (int ks=0; ks<2; ++ks) {
        int ca = (ks*4 + q16) ^ (ra & 7);
        a[mt][ks] = *reinterpret_cast<const s16x8*>(&bufA[ra*64 + ca*8]);
      }
    }
#pragma unroll
    for (int nt=0; nt<4; ++nt) {
      int rb = wn*64 + nt*16 + l15;
#pragma unroll
      for (int ks=0; ks<2; ++ks) {
        int cb = (ks*4 + q16) ^ (rb & 7);
        b[nt][ks] = *reinterpret_cast<const s16x8*>(&bufB[rb*64 + cb*8]);
      }
    }
#pragma unroll
    for (int ks=0; ks<2; ++ks)
#pragma unroll
      for (int mt=0; mt<4; ++mt)
#pragma unroll
        for (int nt=0; nt<4; ++nt)
          acc[mt][nt] = MFMA16(a[mt][ks], b[nt][ks], acc[mt][nt]);
    __syncthreads();
    cur ^= 1;
  }

  float* outc = out + (size_t)b0*12544*384;
#pragma unroll
  for (int nt=0; nt<4; ++nt) {
    int ocol = n0 + wn*64 + nt*16 + l15;
    float bp = bias[ocol];
#pragma unroll
    for (int mt=0; mt<4; ++mt) {
      int orow = m0 + wm*64 + mt*16 + q16*4;
#pragma unroll
      for (int r=0; r<4; ++r)
        outc[(size_t)(orow + r)*384 + ocol] = acc[mt][nt][r] + bp;
    }
  }
}

extern "C" void kernel_launch(void* const* d_in, const int* in_sizes, int n_in,
                              void* d_out, int out_size, void* d_ws, size_t ws_size,
                              hipStream_t stream)
{
  (void)in_sizes; (void)n_in; (void)out_size; (void)ws_size;
  const float* x     = (const float*)d_in[0];
  const float* wqkv  = (const float*)d_in[3];
  const float* lng   = (const float*)d_in[4];
  const float* lnb   = (const float*)d_in[5];
  const float* wqk   = (const float*)d_in[6];
  const float* wproj = (const float*)d_in[7];
  const float* bproj = (const float*)d_in[8];
  float* out = (float*)d_out;

  WS W;
  ws_plan((char*)d_ws, &W);

  // full-batch phase
  k0_prep<<<3456, 256, 0, stream>>>(wqkv, wqk, wproj, W.wfrag, W.wqkT, W.wprojT);
  k1_win_attn<<<4096, 256, 0, stream>>>(x, W.wfrag, lng, lnb, W.pv, W.winp);
  k2_pqk<<<dim3(64, 12), 256, 0, stream>>>(W.winp, W.wqkT, W.pq, W.pk);
  k3_pa<<<dim3(192, 4), 256, 0, stream>>>(W.pq, W.pk, W.pa);

  // chunked phase (4 batches each): working set ~140 MB -> L3-sized
  for (int c = 0; c < 4; ++c) {
    const short* pvc = W.pv + (size_t)c*48*256*1568;
    const short* pac = W.pa + (size_t)c*48*256*256;
    k4_tr<<<dim3(4, 49, 48), 256, 0, stream>>>(pvc, W.pvT);
    k5_po<<<dim3(14, 4, 48), 256, 0, stream>>>(pac, pvc, W.pvT, W.po);
    k6_gemm<<<dim3(392, 3), 256, 0, stream>>>(W.po, W.wprojT, bproj, out, c*4);
  }
}

// Round 16
// 819.739 us; speedup vs baseline: 1.4193x; 1.4193x over previous
//
#include <hip/hip_runtime.h>
#include <hip/hip_bf16.h>
#include <cstdint>

using f32x4 = __attribute__((ext_vector_type(4))) float;
using s16x8 = __attribute__((ext_vector_type(8))) short;
using s16x4 = __attribute__((ext_vector_type(4))) short;

#define MFMA16(A,Bv,Cv) __builtin_amdgcn_mfma_f32_16x16x32_bf16((A),(Bv),(Cv),0,0,0)

__device__ __forceinline__ short f2bf(float f){
  __hip_bfloat16 h = __float2bfloat16(f);           // RNE; compiler fuses pairs to v_cvt_pk_bf16_f32
  union { __hip_bfloat16 h; short s; } u; u.h = h;
  return u.s;
}
__device__ __forceinline__ float bf2f(short s){
  union { unsigned u; float f; } v; v.u = ((unsigned)(unsigned short)s) << 16;
  return v.f;
}
// async global->LDS, 16B per lane; dest = uniform base + lane*16 (HW rule)
__device__ __forceinline__ void gload16(const short* g, short* l){
  __builtin_amdgcn_global_load_lds((const __attribute__((address_space(1))) unsigned int*)g,
                                   (__attribute__((address_space(3))) unsigned int*)l, 16, 0, 0);
}

static constexpr float SCALE_QK = 0.17677669529663687f; // 32^-0.5

// ---- workspace plan: k1/k2/k3 full-batch; k5/k6 chunked (4 batches). k4/pvT eliminated. ----
struct WS {
  short *wfrag, *wqkT, *wprojT, *pv, *winp, *pq, *pk, *pa, *po;
};
static size_t ws_plan(char* base, WS* w) {
  size_t o = 0;
  auto take = [&](size_t bytes) -> short* {
    short* p = (short*)(base + o); o += (bytes + 255) & ~(size_t)255; return p;
  };
  short* wfrag = take((size_t)12*12*6*512*2);      // qkv weights in FRAGMENT order (884 KB)
  short* wqkT  = take((size_t)768*384*2);
  short* wproj = take((size_t)384*384*2);
  short* pv    = take((size_t)16*12*256*1568*2);   // full: 154 MB
  short* winp  = take((size_t)4096*384*2);
  short* pq    = take((size_t)16*12*256*32*2);
  short* pk    = take((size_t)16*12*256*32*2);
  short* pa    = take((size_t)16*12*256*256*2);    // full: 100 MB
  short* po    = take((size_t)4*12544*384*2);      // chunk: 38.5 MB
  if (w) { w->wfrag=wfrag; w->wqkT=wqkT; w->wprojT=wproj; w->pv=pv; w->winp=winp;
           w->pq=pq; w->pk=pk; w->pa=pa; w->po=po; }
  return o;   // ~300 MB
}

// ---------------- k0: weight prep ----------------
// wfrag[hh][ks][half][lane][8]: half 0/1=q lo/hi-16-rows, 2/3=k, 4/5=v; lane=(q16<<4)|l15.
__global__ __launch_bounds__(256) void k0_prep(const float* __restrict__ wqkv,
    const float* __restrict__ wqk, const float* __restrict__ wproj,
    short* __restrict__ wfrag, short* __restrict__ wqkT, short* __restrict__ wprojT)
{
  int i = blockIdx.x * 256 + threadIdx.x;
  if (i < 442368) {
    int j = i & 7, lane = (i >> 3) & 63, half = (i >> 9) % 6, rest = i / 3072;
    int ks = rest % 12, hh = rest / 12;
    int q16 = lane >> 4, l15 = lane & 15;
    int row = (half >> 1)*384 + hh*32 + (half & 1)*16 + l15;
    int col = ks*32 + q16*8 + j;
    wfrag[i] = f2bf(wqkv[(size_t)col*1152 + row]);
    return;
  }
  i -= 442368;
  if (i < 768*384) { int nn = i / 384, kk = i % 384; wqkT[i] = f2bf(wqk[kk*768 + nn]); return; }
  i -= 768*384;
  if (i < 384*384) { int nn = i / 384, kk = i % 384; wprojT[i] = f2bf(wproj[kk*384 + nn]); }
}

// ---------------- k1: fused qkv GEMM + window attention + residual + LN/GELU ----------------
// R14 measured-best body (528us): fused q+k, ksp-SPLIT v-pass, wfrag 1KB weight loads, (256,2).
// [R15]: merging the v-pass ksp split REGRESSED (+9us) — keep the split.
// [R5/R8/R9/R10/R12]: launch_bounds below natural 168 SPILLS. [R13]: s_setprio regressed.
__global__ __launch_bounds__(256, 2) void k1_win_attn(
    const float* __restrict__ x, const short* __restrict__ wfrag,
    const float* __restrict__ lng, const float* __restrict__ lnb,
    short* __restrict__ pv, short* __restrict__ winpost)
{
  __shared__ short xb[52*392];   // rows 0..49 = x bf16 (ld 392); rows 50..51 alias win[384] floats
  __shared__ float rbuf[8];
  float* win = reinterpret_cast<float*>(&xb[50*392]);

  const int tid = threadIdx.x;
  const int w = tid >> 6;
  const int lane = tid & 63;
  const int l15 = lane & 15, q16 = lane >> 4;
  const int wl = blockIdx.x;             // global window (0..4095)
  const int bl = wl >> 8, n = wl & 255;  // batch, window idx

  {
    const float* xp = x + (size_t)wl * (50*384);
    for (int i = tid; i < 4800; i += 256) {
      float4 v = reinterpret_cast<const float4*>(xp)[i];
      int e = i * 4, t = e / 384, k = e % 384;
      short4 s4; s4.x = f2bf(v.x); s4.y = f2bf(v.y); s4.z = f2bf(v.z); s4.w = f2bf(v.w);
      *reinterpret_cast<short4*>(&xb[t*392 + k]) = s4;
    }
  }
  __syncthreads();

  for (int ih = 0; ih < 3; ++ih) {
    const int hh = w*3 + ih;

    // ---- fused q+k pass: Cq = Wq.x^T, Ck = Wk.x^T (shared x B-frags)
    f32x4 cq[2][4], ck[2][4];
#pragma unroll
    for (int mt=0; mt<2; ++mt)
#pragma unroll
      for (int nt=0; nt<4; ++nt) { cq[mt][nt]=f32x4{0.f,0.f,0.f,0.f}; ck[mt][nt]=f32x4{0.f,0.f,0.f,0.f}; }
    for (int ks = 0; ks < 12; ++ks) {
      const short* wfb = wfrag + ((size_t)(hh*12 + ks)*6)*512 + lane*8;
      s16x8 awq0 = *reinterpret_cast<const s16x8*>(wfb);
      s16x8 awq1 = *reinterpret_cast<const s16x8*>(wfb + 512);
      s16x8 awk0 = *reinterpret_cast<const s16x8*>(wfb + 1024);
      s16x8 awk1 = *reinterpret_cast<const s16x8*>(wfb + 1536);
#pragma unroll
      for (int nt=0; nt<4; ++nt) {
        int rr = nt*16 + l15; rr = rr > 51 ? 51 : rr;   // rows 50/51 garbage (win) — col-isolated
        s16x8 bx = *reinterpret_cast<const s16x8*>(&xb[rr*392 + ks*32 + q16*8]);
        cq[0][nt] = MFMA16(awq0, bx, cq[0][nt]);
        cq[1][nt] = MFMA16(awq1, bx, cq[1][nt]);
        ck[0][nt] = MFMA16(awk0, bx, ck[0][nt]);
        ck[1][nt] = MFMA16(awk1, bx, ck[1][nt]);
      }
    }
    // pack fragments in-register (k-map g1(q16,j) = (j>>2)*16 + q16*4 + (j&3)); fold scale into q
    s16x8 qf[4], kf[4];
#pragma unroll
    for (int nt=0; nt<4; ++nt)
#pragma unroll
      for (int j=0; j<8; ++j) {
        qf[nt][j] = f2bf(cq[j>>2][nt][j&3] * SCALE_QK);  // B-frag q[t=l15][dd=g1]
        kf[nt][j] = f2bf(ck[j>>2][nt][j&3]);             // A-frag k[s=l15][dd=g1] (nt = sti)
      }

    // ---- S^T per t-frag: 4 MFMA + no-max softmax (sum only) + pack unnormalized P
    s16x8 pf[4][2];
    float inv4[4];
#pragma unroll
    for (int nt=0; nt<4; ++nt) {
      f32x4 stc[4];
#pragma unroll
      for (int sti=0; sti<4; ++sti) {
        f32x4 z = {0.f,0.f,0.f,0.f};
        stc[sti] = MFMA16(kf[sti], qf[nt], z);
      }
      float sum = 0.f;
#pragma unroll
      for (int sti=0; sti<4; ++sti)
#pragma unroll
        for (int r=0;r<4;++r) {
          int s = sti*16 + q16*4 + r;
          float p = (s < 50) ? __expf(stc[sti][r]) : 0.f;   // garbage rows predicated off
          stc[sti][r] = p; sum += p;
        }
      sum += __shfl_xor(sum, 16);
      sum += __shfl_xor(sum, 32);
      inv4[nt] = 1.f / sum;
#pragma unroll
      for (int ksp=0; ksp<2; ++ksp)
#pragma unroll
        for (int j=0;j<8;++j)
          pf[nt][ksp][j] = f2bf(stc[ksp*2 + (j>>2)][j&3]);
    }

    // ---- v-pass + O^T, split by s-half (ksp) — measured-best schedule
    f32x4 ot[2][4];
#pragma unroll
    for (int mt=0; mt<2; ++mt)
#pragma unroll
      for (int nt=0; nt<4; ++nt) ot[mt][nt] = f32x4{0.f,0.f,0.f,0.f};

#pragma unroll
    for (int ksp=0; ksp<2; ++ksp) {
      f32x4 cvh[2][2];
#pragma unroll
      for (int sg=0; sg<2; ++sg) { cvh[sg][0]=f32x4{0.f,0.f,0.f,0.f}; cvh[sg][1]=f32x4{0.f,0.f,0.f,0.f}; }
      for (int ks=0; ks<12; ++ks) {
        const short* wfb = wfrag + ((size_t)(hh*12 + ks)*6)*512 + lane*8;
        s16x8 bw0 = *reinterpret_cast<const s16x8*>(wfb + 2048);
        s16x8 bw1 = *reinterpret_cast<const s16x8*>(wfb + 2560);
#pragma unroll
        for (int sg=0; sg<2; ++sg){
          int rr = ksp*32 + sg*16 + l15; rr = rr > 51 ? 51 : rr;
          s16x8 ax = *reinterpret_cast<const s16x8*>(&xb[rr*392 + ks*32 + q16*8]);
          cvh[sg][0] = MFMA16(ax, bw0, cvh[sg][0]);
          cvh[sg][1] = MFMA16(ax, bw1, cvh[sg][1]);
        }
      }
#pragma unroll
      for (int mt=0; mt<2; ++mt) {
        s16x8 vf;
#pragma unroll
        for (int j=0;j<8;++j) {
          int s = ksp*32 + (j>>2)*16 + q16*4 + (j&3);
          vf[j] = (s < 50) ? f2bf(cvh[j>>2][mt][j&3]) : (short)0;   // guard garbage rows
        }
#pragma unroll
        for (int nt=0; nt<4; ++nt) ot[mt][nt] = MFMA16(vf, pf[nt][ksp], ot[mt][nt]);
      }
    }

    // ---- epilogue: apply deferred inv + residual + scatter
    short* pvb = pv + (((size_t)bl*12 + hh)*256 + n) * 1568;
#pragma unroll
    for (int nt=0; nt<4; ++nt) {
      int t = nt*16 + l15;
      if (t >= 1 && t < 50) {
#pragma unroll
        for (int mt=0; mt<2; ++mt) {
          short4 s4;
#pragma unroll
          for (int r=0;r<4;++r) {
            int dd = mt*16 + q16*4 + r;
            float val = ot[mt][nt][r] * inv4[nt] + bf2f(xb[t*392 + hh*32 + dd]);
            ((short*)&s4)[r] = f2bf(val);
          }
          *reinterpret_cast<short4*>(&pvb[(size_t)(t-1)*32 + mt*16 + q16*4]) = s4;
        }
      } else if (t == 0) {
#pragma unroll
        for (int mt=0; mt<2; ++mt)
#pragma unroll
          for (int r=0;r<4;++r) {
            int dd = mt*16 + q16*4 + r;
            win[hh*32 + dd] = ot[mt][nt][r] * inv4[nt] + bf2f(xb[hh*32 + dd]);
          }
      }
    }
  }

  __syncthreads();
  // ---- LayerNorm + exact GELU on window token
  float s1 = 0.f, s2 = 0.f;
  for (int c = tid; c < 384; c += 256) { float v = win[c]; s1 += v; s2 += v*v; }
#pragma unroll
  for (int o = 32; o >= 1; o >>= 1) { s1 += __shfl_xor(s1, o); s2 += __shfl_xor(s2, o); }
  if (lane == 0) { rbuf[w] = s1; rbuf[4+w] = s2; }
  __syncthreads();
  s1 = rbuf[0] + rbuf[1] + rbuf[2] + rbuf[3];
  s2 = rbuf[4] + rbuf[5] + rbuf[6] + rbuf[7];
  float mean = s1 * (1.f/384.f);
  float var  = s2 * (1.f/384.f) - mean*mean;
  float rstd = rsqrtf(var + 1e-5f);
  for (int c = tid; c < 384; c += 256) {
    float xn = (win[c] - mean) * rstd * lng[c] + lnb[c];
    float ge = 0.5f * xn * (1.f + erff(xn * 0.70710678118654752f));
    winpost[(size_t)wl*384 + c] = f2bf(ge);
  }
}

// ---------------- k2: pq/pk = win_post @ W_qk; SCALE_QK folded into pq (full batch) ----------------
__global__ __launch_bounds__(256) void k2_pqk(const short* __restrict__ winp,
    const short* __restrict__ wqkT, short* __restrict__ pq, short* __restrict__ pk)
{
  const int tid = threadIdx.x;
  const int w = tid >> 6, lane = tid & 63;
  const int l15 = lane & 15, q16 = lane >> 4;
  const int m0 = blockIdx.x * 64, n0 = blockIdx.y * 64;
  f32x4 acc[4];
#pragma unroll
  for (int nt=0; nt<4; ++nt) acc[nt] = f32x4{0.f,0.f,0.f,0.f};
  const int mrow = m0 + w*16 + l15;
  for (int ks2=0; ks2<12; ++ks2) {
    s16x8 a = *reinterpret_cast<const s16x8*>(winp + (size_t)mrow*384 + ks2*32 + q16*8);
#pragma unroll
    for (int nt=0; nt<4; ++nt) {
      s16x8 bf = *reinterpret_cast<const s16x8*>(wqkT + (size_t)(n0 + nt*16 + l15)*384 + ks2*32 + q16*8);
      acc[nt] = MFMA16(a, bf, acc[nt]);
    }
  }
#pragma unroll
  for (int nt=0; nt<4; ++nt)
#pragma unroll
    for (int r=0; r<4; ++r) {
      int m = m0 + w*16 + q16*4 + r;
      int bb = m >> 8, nn = m & 255;
      int c = n0 + nt*16 + l15;
      short* dst = (c >= 384) ? pk : pq;
      float v = acc[nt][r];
      if (c < 384) v *= SCALE_QK;        // fold scale into pq
      int hc = (c >= 384) ? (c - 384) : c;
      int hh = hc >> 5, dd = hc & 31;
      dst[(((size_t)bb*12 + hh)*256 + nn)*32 + dd] = f2bf(v);
    }
}

// ---------------- k3: pa = softmax(pq . pk^T) — 4x row-parallel (grid 192x4) ----------------
__global__ __launch_bounds__(256) void k3_pa(const short* __restrict__ pq,
    const short* __restrict__ pk, short* __restrict__ pa)
{
  __shared__ short ql[64*40];
  __shared__ short kl2[256*40];
  const int tid = threadIdx.x;
  const int w = tid >> 6, lane = tid & 63;
  const int l15 = lane & 15, q16 = lane >> 4;
  const int bh = blockIdx.x, by = blockIdx.y;
  const short* qs = pq + (size_t)bh * 8192;
  const short* ksp = pk + (size_t)bh * 8192;
  {
    int nn = tid >> 2, dd = (tid & 3) * 8;   // ql quarter: rows by*64..+64
    *reinterpret_cast<s16x8*>(&ql[nn*40 + dd]) =
        *reinterpret_cast<const s16x8*>(qs + (size_t)(by*64 + nn)*32 + dd);
  }
  for (int i = tid; i < 1024; i += 256) {
    int nn = i >> 2, dd = (i & 3) * 8;
    *reinterpret_cast<s16x8*>(&kl2[nn*40 + dd]) = *reinterpret_cast<const s16x8*>(ksp + i*8);
  }
  __syncthreads();
  s16x8 a = *reinterpret_cast<const s16x8*>(&ql[(w*16 + l15)*40 + q16*8]);
  f32x4 acc[16];
#pragma unroll
  for (int nt=0; nt<16; ++nt) {
    s16x8 bf = *reinterpret_cast<const s16x8*>(&kl2[(nt*16 + l15)*40 + q16*8]);
    f32x4 z = {0.f,0.f,0.f,0.f};
    acc[nt] = MFMA16(a, bf, z);
  }
#pragma unroll
  for (int r=0; r<4; ++r) {
    float sum = 0.f;
#pragma unroll
    for (int nt=0; nt<16; ++nt) { float p = __expf(acc[nt][r]); acc[nt][r] = p; sum += p; }
    sum += __shfl_xor(sum, 1); sum += __shfl_xor(sum, 2);
    sum += __shfl_xor(sum, 4); sum += __shfl_xor(sum, 8);
    float inv = 1.f / sum;
    int row = by*64 + w*16 + q16*4 + r;
    short* dst = pa + ((size_t)bh*256 + row) * 256;
#pragma unroll
    for (int nt=0; nt<16; ++nt) dst[nt*16 + l15] = f2bf(acc[nt][r] * inv);
  }
}

// ---------------- k5: po = pa @ pv + residual; pv transposed IN-LDS (k4 eliminated) ----------------
// Block: 512 thr (8 waves), covers [256 n-rows] x [112 cols] of one bh.
// Stage vt[c][n] (pad 264: rows 16B-aligned, <=2-way conflicts) from coalesced pv row reads;
// B-frags become ds_read_b128 from vt; residual reads come from the same tile.
__global__ __launch_bounds__(512) void k5_po(const short* __restrict__ pa,
    const short* __restrict__ pv, short* __restrict__ po)
{
  __shared__ short vt[112*264];   // 59.1 KB
  const int tid = threadIdx.x;
  const int w = tid >> 6, lane = tid & 63;
  const int l15 = lane & 15, q16 = lane >> 4;
  const int c0 = blockIdx.x * 112;
  const int bh = blockIdx.y;
  const short* pab = pa + (size_t)bh * 256 * 256;
  const short* pvs = pv + (size_t)bh * 256 * 1568;

  // stage pv[0:256][c0:c0+112] -> vt[c_local][n]
  {
    const int n = tid >> 1, half = tid & 1;
    const short* rowp = pvs + (size_t)n*1568 + c0 + half*56;
#pragma unroll
    for (int jj = 0; jj < 7; ++jj) {
      s16x8 v = *reinterpret_cast<const s16x8*>(rowp + jj*8);
#pragma unroll
      for (int j = 0; j < 8; ++j)
        vt[(half*56 + jj*8 + j)*264 + n] = v[j];
    }
  }
  __syncthreads();

  f32x4 acc[2][7];
#pragma unroll
  for (int mt=0; mt<2; ++mt)
#pragma unroll
    for (int nt=0; nt<7; ++nt) acc[mt][nt] = f32x4{0.f,0.f,0.f,0.f};

  const int mrow = w*32;
  for (int ks2 = 0; ks2 < 8; ++ks2) {
    s16x8 a0 = *reinterpret_cast<const s16x8*>(pab + (size_t)(mrow + l15)*256 + ks2*32 + q16*8);
    s16x8 a1 = *reinterpret_cast<const s16x8*>(pab + (size_t)(mrow + 16 + l15)*256 + ks2*32 + q16*8);
#pragma unroll
    for (int nt=0; nt<7; ++nt) {
      s16x8 bf = *reinterpret_cast<const s16x8*>(&vt[(nt*16 + l15)*264 + ks2*32 + q16*8]);
      acc[0][nt] = MFMA16(a0, bf, acc[0][nt]);
      acc[1][nt] = MFMA16(a1, bf, acc[1][nt]);
    }
  }

  const int bl = bh / 12, hh = bh % 12;
#pragma unroll
  for (int nt=0; nt<7; ++nt)
#pragma unroll
    for (int mt=0; mt<2; ++mt)
#pragma unroll
      for (int r=0; r<4; ++r) {
        int nn = mrow + mt*16 + q16*4 + r;
        int cl = nt*16 + l15;
        float val = acc[mt][nt][r] + bf2f(vt[cl*264 + nn]);   // residual from LDS tile
        int col = c0 + cl;
        int wp2 = col >> 5, dd = col & 31;
        int y = (nn >> 4)*7 + wp2/7, xx = (nn & 15)*7 + wp2%7;
        po[((size_t)bl*12544 + y*112 + xx)*384 + hh*32 + dd] = f2bf(val);
      }
}

// ---------------- k6: linear GEMM out = po_lin @ wprojT^T + bias (m97 structure + T2 swizzle) ----------------
__global__ __launch_bounds__(256) void k6_gemm(const short* __restrict__ A,
    const short* __restrict__ Bw, const float* __restrict__ bias,
    float* __restrict__ out, int b0)
{
  __shared__ short lA[2][128*64];
  __shared__ short lB[2][128*64];
  const int tid = threadIdx.x;
  const int w = tid >> 6, lane = tid & 63;
  const int l15 = lane & 15, q16 = lane >> 4;
  const int m0 = blockIdx.x * 128, n0 = blockIdx.y * 128;

  const int srow = lane >> 3;
  const int c16s = (lane & 7) ^ srow;
  const short* aSrc0 = A  + (size_t)(m0 + w*32 + srow)*384 + c16s*8;
  const short* bSrc0 = Bw + (size_t)(n0 + w*32 + srow)*384 + c16s*8;

  f32x4 acc[4][4];
#pragma unroll
  for (int mt=0; mt<4; ++mt)
#pragma unroll
    for (int nt=0; nt<4; ++nt) acc[mt][nt] = f32x4{0.f,0.f,0.f,0.f};

  const int wm = w >> 1, wn = w & 1;

#pragma unroll
  for (int j=0; j<4; ++j) {
    gload16(aSrc0 + j*8*384, &lA[0][(w*4 + j)*512]);
    gload16(bSrc0 + j*8*384, &lB[0][(w*4 + j)*512]);
  }
  __syncthreads();

  int cur = 0;
  for (int t = 0; t < 6; ++t) {
    if (t < 5) {
      const short* aS = aSrc0 + (t+1)*64;
      const short* bS = bSrc0 + (t+1)*64;
#pragma unroll
      for (int j=0; j<4; ++j) {
        gload16(aS + j*8*384, &lA[cur^1][(w*4 + j)*512]);
        gload16(bS + j*8*384, &lB[cur^1][(w*4 + j)*512]);
      }
    }
    const short* bufA = lA[cur];
    const short* bufB = lB[cur];
    s16x8 a[4][2], b[4][2];
#pragma unroll
    for (int mt=0; mt<4; ++mt) {
      int ra = wm*64 + mt*16 + l15;
#pragma unroll
      for (int ks=0; ks<2; ++ks) {
        int ca = (ks*4 + q16) ^ (ra & 7);
        a[mt][ks] = *reinterpret_cast<const s16x8*>(&bufA[ra*64 + ca*8]);
      }
    }
#pragma unroll
    for (int nt=0; nt<4; ++nt) {
      int rb = wn*64 + nt*16 + l15;
#pragma unroll
      for (int ks=0; ks<2; ++ks) {
        int cb = (ks*4 + q16) ^ (rb & 7);
        b[nt][ks] = *reinterpret_cast<const s16x8*>(&bufB[rb*64 + cb*8]);
      }
    }
#pragma unroll
    for (int ks=0; ks<2; ++ks)
#pragma unroll
      for (int mt=0; mt<4; ++mt)
#pragma unroll
        for (int nt=0; nt<4; ++nt)
          acc[mt][nt] = MFMA16(a[mt][ks], b[nt][ks], acc[mt][nt]);
    __syncthreads();
    cur ^= 1;
  }

  float* outc = out + (size_t)b0*12544*384;
#pragma unroll
  for (int nt=0; nt<4; ++nt) {
    int ocol = n0 + wn*64 + nt*16 + l15;
    float bp = bias[ocol];
#pragma unroll
    for (int mt=0; mt<4; ++mt) {
      int orow = m0 + wm*64 + mt*16 + q16*4;
#pragma unroll
      for (int r=0; r<4; ++r)
        outc[(size_t)(orow + r)*384 + ocol] = acc[mt][nt][r] + bp;
    }
  }
}

extern "C" void kernel_launch(void* const* d_in, const int* in_sizes, int n_in,
                              void* d_out, int out_size, void* d_ws, size_t ws_size,
                              hipStream_t stream)
{
  (void)in_sizes; (void)n_in; (void)out_size; (void)ws_size;
  const float* x     = (const float*)d_in[0];
  const float* wqkv  = (const float*)d_in[3];
  const float* lng   = (const float*)d_in[4];
  const float* lnb   = (const float*)d_in[5];
  const float* wqk   = (const float*)d_in[6];
  const float* wproj = (const float*)d_in[7];
  const float* bproj = (const float*)d_in[8];
  float* out = (float*)d_out;

  WS W;
  ws_plan((char*)d_ws, &W);

  // full-batch phase
  k0_prep<<<3456, 256, 0, stream>>>(wqkv, wqk, wproj, W.wfrag, W.wqkT, W.wprojT);
  k1_win_attn<<<4096, 256, 0, stream>>>(x, W.wfrag, lng, lnb, W.pv, W.winp);
  k2_pqk<<<dim3(64, 12), 256, 0, stream>>>(W.winp, W.wqkT, W.pq, W.pk);
  k3_pa<<<dim3(192, 4), 256, 0, stream>>>(W.pq, W.pk, W.pa);

  // chunked phase (4 batches each): working set ~85 MB -> L3-resident
  for (int c = 0; c < 4; ++c) {
    const short* pvc = W.pv + (size_t)c*48*256*1568;
    const short* pac = W.pa + (size_t)c*48*256*256;
    k5_po<<<dim3(14, 48), 512, 0, stream>>>(pac, pvc, W.po);
    k6_gemm<<<dim3(392, 3), 256, 0, stream>>>(W.po, W.wprojT, bproj, out, c*4);
  }
}

// Round 17
// 651.708 us; speedup vs baseline: 1.7853x; 1.2578x over previous
//
#include <hip/hip_runtime.h>
#include <hip/hip_bf16.h>
#include <cstdint>

using f32x4 = __attribute__((ext_vector_type(4))) float;
using s16x8 = __attribute__((ext_vector_type(8))) short;
using s16x4 = __attribute__((ext_vector_type(4))) short;

#define MFMA16(A,Bv,Cv) __builtin_amdgcn_mfma_f32_16x16x32_bf16((A),(Bv),(Cv),0,0,0)

__device__ __forceinline__ short f2bf(float f){
  __hip_bfloat16 h = __float2bfloat16(f);           // RNE; compiler fuses pairs to v_cvt_pk_bf16_f32
  union { __hip_bfloat16 h; short s; } u; u.h = h;
  return u.s;
}
__device__ __forceinline__ float bf2f(short s){
  union { unsigned u; float f; } v; v.u = ((unsigned)(unsigned short)s) << 16;
  return v.f;
}
// async global->LDS, 16B per lane; dest = uniform base + lane*16 (HW rule)
__device__ __forceinline__ void gload16(const short* g, short* l){
  __builtin_amdgcn_global_load_lds((const __attribute__((address_space(1))) unsigned int*)g,
                                   (__attribute__((address_space(3))) unsigned int*)l, 16, 0, 0);
}

static constexpr float SCALE_QK = 0.17677669529663687f; // 32^-0.5

// ---- workspace plan: k1/k2/k3 full-batch; k5/k6 chunked (4 batches). k4/pvT eliminated. ----
struct WS {
  short *wfrag, *wqkT, *wprojT, *pv, *winp, *pq, *pk, *pa, *po;
};
static size_t ws_plan(char* base, WS* w) {
  size_t o = 0;
  auto take = [&](size_t bytes) -> short* {
    short* p = (short*)(base + o); o += (bytes + 255) & ~(size_t)255; return p;
  };
  short* wfrag = take((size_t)12*12*6*512*2);      // qkv weights in FRAGMENT order (884 KB)
  short* wqkT  = take((size_t)768*384*2);
  short* wproj = take((size_t)384*384*2);
  short* pv    = take((size_t)16*12*256*1568*2);   // full: 154 MB
  short* winp  = take((size_t)4096*384*2);
  short* pq    = take((size_t)16*12*256*32*2);
  short* pk    = take((size_t)16*12*256*32*2);
  short* pa    = take((size_t)16*12*256*256*2);    // full: 100 MB
  short* po    = take((size_t)4*12544*384*2);      // chunk: 38.5 MB
  if (w) { w->wfrag=wfrag; w->wqkT=wqkT; w->wprojT=wproj; w->pv=pv; w->winp=winp;
           w->pq=pq; w->pk=pk; w->pa=pa; w->po=po; }
  return o;   // ~300 MB
}

// ---------------- k0: weight prep ----------------
// wfrag[hh][ks][half][lane][8]: half 0/1=q lo/hi-16-rows, 2/3=k, 4/5=v; lane=(q16<<4)|l15.
__global__ __launch_bounds__(256) void k0_prep(const float* __restrict__ wqkv,
    const float* __restrict__ wqk, const float* __restrict__ wproj,
    short* __restrict__ wfrag, short* __restrict__ wqkT, short* __restrict__ wprojT)
{
  int i = blockIdx.x * 256 + threadIdx.x;
  if (i < 442368) {
    int j = i & 7, lane = (i >> 3) & 63, half = (i >> 9) % 6, rest = i / 3072;
    int ks = rest % 12, hh = rest / 12;
    int q16 = lane >> 4, l15 = lane & 15;
    int row = (half >> 1)*384 + hh*32 + (half & 1)*16 + l15;
    int col = ks*32 + q16*8 + j;
    wfrag[i] = f2bf(wqkv[(size_t)col*1152 + row]);
    return;
  }
  i -= 442368;
  if (i < 768*384) { int nn = i / 384, kk = i % 384; wqkT[i] = f2bf(wqk[kk*768 + nn]); return; }
  i -= 768*384;
  if (i < 384*384) { int nn = i / 384, kk = i % 384; wprojT[i] = f2bf(wproj[kk*384 + nn]); }
}

// ---------------- k1: fused qkv GEMM + window attention + residual + LN/GELU ----------------
// FUSED q+k+v single K-sweep: 24 MFMA/iter in 6 chains, 6 wave-contiguous 1KB weight loads,
// bx[] serves as B-op for q/k AND A-op for v (both natural g0 k-map). 12 iters/head (was 36).
// Peak regs ~96 AGPR + ~100 arch < (256,2) cap of 256 -> no spill expected; occupancy unchanged.
// [R5..R12]: caps below natural demand SPILL. [R13]: setprio regressed. O^T indexing = R15-verified.
__global__ __launch_bounds__(256, 2) void k1_win_attn(
    const float* __restrict__ x, const short* __restrict__ wfrag,
    const float* __restrict__ lng, const float* __restrict__ lnb,
    short* __restrict__ pv, short* __restrict__ winpost)
{
  __shared__ short xb[52*392];   // rows 0..49 = x bf16 (ld 392); rows 50..51 alias win[384] floats
  __shared__ float rbuf[8];
  float* win = reinterpret_cast<float*>(&xb[50*392]);

  const int tid = threadIdx.x;
  const int w = tid >> 6;
  const int lane = tid & 63;
  const int l15 = lane & 15, q16 = lane >> 4;
  const int wl = blockIdx.x;             // global window (0..4095)
  const int bl = wl >> 8, n = wl & 255;  // batch, window idx

  {
    const float* xp = x + (size_t)wl * (50*384);
    for (int i = tid; i < 4800; i += 256) {
      float4 v = reinterpret_cast<const float4*>(xp)[i];
      int e = i * 4, t = e / 384, k = e % 384;
      short4 s4; s4.x = f2bf(v.x); s4.y = f2bf(v.y); s4.z = f2bf(v.z); s4.w = f2bf(v.w);
      *reinterpret_cast<short4*>(&xb[t*392 + k]) = s4;
    }
  }
  __syncthreads();

  for (int ih = 0; ih < 3; ++ih) {
    const int hh = w*3 + ih;

    // ---- fused q+k+v pass: Cq = Wq.x^T, Ck = Wk.x^T, Cv = x.Wv^T (shared bx)
    f32x4 cq[2][4], ck[2][4], cv[4][2];
#pragma unroll
    for (int mt=0; mt<2; ++mt)
#pragma unroll
      for (int nt=0; nt<4; ++nt) { cq[mt][nt]=f32x4{0.f,0.f,0.f,0.f}; ck[mt][nt]=f32x4{0.f,0.f,0.f,0.f}; }
#pragma unroll
    for (int sg=0; sg<4; ++sg) { cv[sg][0]=f32x4{0.f,0.f,0.f,0.f}; cv[sg][1]=f32x4{0.f,0.f,0.f,0.f}; }

    for (int ks = 0; ks < 12; ++ks) {
      const short* wfb = wfrag + ((size_t)(hh*12 + ks)*6)*512 + lane*8;
      s16x8 awq0 = *reinterpret_cast<const s16x8*>(wfb);
      s16x8 awq1 = *reinterpret_cast<const s16x8*>(wfb + 512);
      s16x8 awk0 = *reinterpret_cast<const s16x8*>(wfb + 1024);
      s16x8 awk1 = *reinterpret_cast<const s16x8*>(wfb + 1536);
      s16x8 bwv0 = *reinterpret_cast<const s16x8*>(wfb + 2048);
      s16x8 bwv1 = *reinterpret_cast<const s16x8*>(wfb + 2560);
      s16x8 bx[4];
#pragma unroll
      for (int nt=0; nt<4; ++nt) {
        int rr = nt*16 + l15; rr = rr > 51 ? 51 : rr;   // rows 50/51 garbage (win) — col-isolated
        bx[nt] = *reinterpret_cast<const s16x8*>(&xb[rr*392 + ks*32 + q16*8]);
      }
#pragma unroll
      for (int nt=0; nt<4; ++nt) {
        cq[0][nt] = MFMA16(awq0, bx[nt], cq[0][nt]);
        cq[1][nt] = MFMA16(awq1, bx[nt], cq[1][nt]);
        ck[0][nt] = MFMA16(awk0, bx[nt], ck[0][nt]);
        ck[1][nt] = MFMA16(awk1, bx[nt], ck[1][nt]);
        cv[nt][0] = MFMA16(bx[nt], bwv0, cv[nt][0]);
        cv[nt][1] = MFMA16(bx[nt], bwv1, cv[nt][1]);
      }
    }

    // pack q/k fragments (k-map g1(q16,j) = (j>>2)*16 + q16*4 + (j&3)); fold scale into q
    s16x8 qf[4], kf[4];
#pragma unroll
    for (int nt=0; nt<4; ++nt)
#pragma unroll
      for (int j=0; j<8; ++j) {
        qf[nt][j] = f2bf(cq[j>>2][nt][j&3] * SCALE_QK);  // B-frag q[t=l15][dd=g1]
        kf[nt][j] = f2bf(ck[j>>2][nt][j&3]);             // A-frag k[s=l15][dd=g1] (nt = sti)
      }

    // ---- S^T per t-frag: 4 MFMA + no-max softmax (sum only) + pack unnormalized P
    s16x8 pf[4][2];
    float inv4[4];
#pragma unroll
    for (int nt=0; nt<4; ++nt) {
      f32x4 stc[4];
#pragma unroll
      for (int sti=0; sti<4; ++sti) {
        f32x4 z = {0.f,0.f,0.f,0.f};
        stc[sti] = MFMA16(kf[sti], qf[nt], z);
      }
      float sum = 0.f;
#pragma unroll
      for (int sti=0; sti<4; ++sti)
#pragma unroll
        for (int r=0;r<4;++r) {
          int s = sti*16 + q16*4 + r;
          float p = (s < 50) ? __expf(stc[sti][r]) : 0.f;   // garbage rows predicated off
          stc[sti][r] = p; sum += p;
        }
      sum += __shfl_xor(sum, 16);
      sum += __shfl_xor(sum, 32);
      inv4[nt] = 1.f / sum;
#pragma unroll
      for (int ksp=0; ksp<2; ++ksp)
#pragma unroll
        for (int j=0;j<8;++j)
          pf[nt][ksp][j] = f2bf(stc[ksp*2 + (j>>2)][j&3]);
    }

    // ---- O^T = vT . P^T (K=64 over s); vf guarded s<50  [R15-verified indexing]
    f32x4 ot[2][4];
#pragma unroll
    for (int mt=0; mt<2; ++mt)
#pragma unroll
      for (int nt=0; nt<4; ++nt) ot[mt][nt] = f32x4{0.f,0.f,0.f,0.f};
#pragma unroll
    for (int ksp=0; ksp<2; ++ksp)
#pragma unroll
      for (int mt=0; mt<2; ++mt) {
        s16x8 vf;
#pragma unroll
        for (int j=0;j<8;++j) {
          int s = ksp*32 + (j>>2)*16 + q16*4 + (j&3);
          vf[j] = (s < 50) ? f2bf(cv[ksp*2 + (j>>2)][mt][j&3]) : (short)0;
        }
#pragma unroll
        for (int nt=0; nt<4; ++nt) ot[mt][nt] = MFMA16(vf, pf[nt][ksp], ot[mt][nt]);
      }

    // ---- epilogue: apply deferred inv + residual + scatter
    short* pvb = pv + (((size_t)bl*12 + hh)*256 + n) * 1568;
#pragma unroll
    for (int nt=0; nt<4; ++nt) {
      int t = nt*16 + l15;
      if (t >= 1 && t < 50) {
#pragma unroll
        for (int mt=0; mt<2; ++mt) {
          short4 s4;
#pragma unroll
          for (int r=0;r<4;++r) {
            int dd = mt*16 + q16*4 + r;
            float val = ot[mt][nt][r] * inv4[nt] + bf2f(xb[t*392 + hh*32 + dd]);
            ((short*)&s4)[r] = f2bf(val);
          }
          *reinterpret_cast<short4*>(&pvb[(size_t)(t-1)*32 + mt*16 + q16*4]) = s4;
        }
      } else if (t == 0) {
#pragma unroll
        for (int mt=0; mt<2; ++mt)
#pragma unroll
          for (int r=0;r<4;++r) {
            int dd = mt*16 + q16*4 + r;
            win[hh*32 + dd] = ot[mt][nt][r] * inv4[nt] + bf2f(xb[hh*32 + dd]);
          }
      }
    }
  }

  __syncthreads();
  // ---- LayerNorm + exact GELU on window token
  float s1 = 0.f, s2 = 0.f;
  for (int c = tid; c < 384; c += 256) { float v = win[c]; s1 += v; s2 += v*v; }
#pragma unroll
  for (int o = 32; o >= 1; o >>= 1) { s1 += __shfl_xor(s1, o); s2 += __shfl_xor(s2, o); }
  if (lane == 0) { rbuf[w] = s1; rbuf[4+w] = s2; }
  __syncthreads();
  s1 = rbuf[0] + rbuf[1] + rbuf[2] + rbuf[3];
  s2 = rbuf[4] + rbuf[5] + rbuf[6] + rbuf[7];
  float mean = s1 * (1.f/384.f);
  float var  = s2 * (1.f/384.f) - mean*mean;
  float rstd = rsqrtf(var + 1e-5f);
  for (int c = tid; c < 384; c += 256) {
    float xn = (win[c] - mean) * rstd * lng[c] + lnb[c];
    float ge = 0.5f * xn * (1.f + erff(xn * 0.70710678118654752f));
    winpost[(size_t)wl*384 + c] = f2bf(ge);
  }
}

// ---------------- k2: pq/pk = win_post @ W_qk; SCALE_QK folded into pq (full batch) ----------------
__global__ __launch_bounds__(256) void k2_pqk(const short* __restrict__ winp,
    const short* __restrict__ wqkT, short* __restrict__ pq, short* __restrict__ pk)
{
  const int tid = threadIdx.x;
  const int w = tid >> 6, lane = tid & 63;
  const int l15 = lane & 15, q16 = lane >> 4;
  const int m0 = blockIdx.x * 64, n0 = blockIdx.y * 64;
  f32x4 acc[4];
#pragma unroll
  for (int nt=0; nt<4; ++nt) acc[nt] = f32x4{0.f,0.f,0.f,0.f};
  const int mrow = m0 + w*16 + l15;
  for (int ks2=0; ks2<12; ++ks2) {
    s16x8 a = *reinterpret_cast<const s16x8*>(winp + (size_t)mrow*384 + ks2*32 + q16*8);
#pragma unroll
    for (int nt=0; nt<4; ++nt) {
      s16x8 bf = *reinterpret_cast<const s16x8*>(wqkT + (size_t)(n0 + nt*16 + l15)*384 + ks2*32 + q16*8);
      acc[nt] = MFMA16(a, bf, acc[nt]);
    }
  }
#pragma unroll
  for (int nt=0; nt<4; ++nt)
#pragma unroll
    for (int r=0; r<4; ++r) {
      int m = m0 + w*16 + q16*4 + r;
      int bb = m >> 8, nn = m & 255;
      int c = n0 + nt*16 + l15;
      short* dst = (c >= 384) ? pk : pq;
      float v = acc[nt][r];
      if (c < 384) v *= SCALE_QK;        // fold scale into pq
      int hc = (c >= 384) ? (c - 384) : c;
      int hh = hc >> 5, dd = hc & 31;
      dst[(((size_t)bb*12 + hh)*256 + nn)*32 + dd] = f2bf(v);
    }
}

// ---------------- k3: pa = softmax(pq . pk^T) — 4x row-parallel (grid 192x4) ----------------
__global__ __launch_bounds__(256) void k3_pa(const short* __restrict__ pq,
    const short* __restrict__ pk, short* __restrict__ pa)
{
  __shared__ short ql[64*40];
  __shared__ short kl2[256*40];
  const int tid = threadIdx.x;
  const int w = tid >> 6, lane = tid & 63;
  const int l15 = lane & 15, q16 = lane >> 4;
  const int bh = blockIdx.x, by = blockIdx.y;
  const short* qs = pq + (size_t)bh * 8192;
  const short* ksp = pk + (size_t)bh * 8192;
  {
    int nn = tid >> 2, dd = (tid & 3) * 8;   // ql quarter: rows by*64..+64
    *reinterpret_cast<s16x8*>(&ql[nn*40 + dd]) =
        *reinterpret_cast<const s16x8*>(qs + (size_t)(by*64 + nn)*32 + dd);
  }
  for (int i = tid; i < 1024; i += 256) {
    int nn = i >> 2, dd = (i & 3) * 8;
    *reinterpret_cast<s16x8*>(&kl2[nn*40 + dd]) = *reinterpret_cast<const s16x8*>(ksp + i*8);
  }
  __syncthreads();
  s16x8 a = *reinterpret_cast<const s16x8*>(&ql[(w*16 + l15)*40 + q16*8]);
  f32x4 acc[16];
#pragma unroll
  for (int nt=0; nt<16; ++nt) {
    s16x8 bf = *reinterpret_cast<const s16x8*>(&kl2[(nt*16 + l15)*40 + q16*8]);
    f32x4 z = {0.f,0.f,0.f,0.f};
    acc[nt] = MFMA16(a, bf, z);
  }
#pragma unroll
  for (int r=0; r<4; ++r) {
    float sum = 0.f;
#pragma unroll
    for (int nt=0; nt<16; ++nt) { float p = __expf(acc[nt][r]); acc[nt][r] = p; sum += p; }
    sum += __shfl_xor(sum, 1); sum += __shfl_xor(sum, 2);
    sum += __shfl_xor(sum, 4); sum += __shfl_xor(sum, 8);
    float inv = 1.f / sum;
    int row = by*64 + w*16 + q16*4 + r;
    short* dst = pa + ((size_t)bh*256 + row) * 256;
#pragma unroll
    for (int nt=0; nt<16; ++nt) dst[nt*16 + l15] = f2bf(acc[nt][r] * inv);
  }
}

// ---------------- k5: po = pa @ pv + residual; pv transposed IN-LDS (k4 eliminated) ----------------
__global__ __launch_bounds__(512) void k5_po(const short* __restrict__ pa,
    const short* __restrict__ pv, short* __restrict__ po)
{
  __shared__ short vt[112*264];   // 59.1 KB
  const int tid = threadIdx.x;
  const int w = tid >> 6, lane = tid & 63;
  const int l15 = lane & 15, q16 = lane >> 4;
  const int c0 = blockIdx.x * 112;
  const int bh = blockIdx.y;
  const short* pab = pa + (size_t)bh * 256 * 256;
  const short* pvs = pv + (size_t)bh * 256 * 1568;

  // stage pv[0:256][c0:c0+112] -> vt[c_local][n]
  {
    const int n = tid >> 1, half = tid & 1;
    const short* rowp = pvs + (size_t)n*1568 + c0 + half*56;
#pragma unroll
    for (int jj = 0; jj < 7; ++jj) {
      s16x8 v = *reinterpret_cast<const s16x8*>(rowp + jj*8);
#pragma unroll
      for (int j = 0; j < 8; ++j)
        vt[(half*56 + jj*8 + j)*264 + n] = v[j];
    }
  }
  __syncthreads();

  f32x4 acc[2][7];
#pragma unroll
  for (int mt=0; mt<2; ++mt)
#pragma unroll
    for (int nt=0; nt<7; ++nt) acc[mt][nt] = f32x4{0.f,0.f,0.f,0.f};

  const int mrow = w*32;
  for (int ks2 = 0; ks2 < 8; ++ks2) {
    s16x8 a0 = *reinterpret_cast<const s16x8*>(pab + (size_t)(mrow + l15)*256 + ks2*32 + q16*8);
    s16x8 a1 = *reinterpret_cast<const s16x8*>(pab + (size_t)(mrow + 16 + l15)*256 + ks2*32 + q16*8);
#pragma unroll
    for (int nt=0; nt<7; ++nt) {
      s16x8 bf = *reinterpret_cast<const s16x8*>(&vt[(nt*16 + l15)*264 + ks2*32 + q16*8]);
      acc[0][nt] = MFMA16(a0, bf, acc[0][nt]);
      acc[1][nt] = MFMA16(a1, bf, acc[1][nt]);
    }
  }

  const int bl = bh / 12, hh = bh % 12;
#pragma unroll
  for (int nt=0; nt<7; ++nt)
#pragma unroll
    for (int mt=0; mt<2; ++mt)
#pragma unroll
      for (int r=0; r<4; ++r) {
        int nn = mrow + mt*16 + q16*4 + r;
        int cl = nt*16 + l15;
        float val = acc[mt][nt][r] + bf2f(vt[cl*264 + nn]);   // residual from LDS tile
        int col = c0 + cl;
        int wp2 = col >> 5, dd = col & 31;
        int y = (nn >> 4)*7 + wp2/7, xx = (nn & 15)*7 + wp2%7;
        po[((size_t)bl*12544 + y*112 + xx)*384 + hh*32 + dd] = f2bf(val);
      }
}

// ---------------- k6: linear GEMM out = po_lin @ wprojT^T + bias (m97 structure + T2 swizzle) ----------------
__global__ __launch_bounds__(256) void k6_gemm(const short* __restrict__ A,
    const short* __restrict__ Bw, const float* __restrict__ bias,
    float* __restrict__ out, int b0)
{
  __shared__ short lA[2][128*64];
  __shared__ short lB[2][128*64];
  const int tid = threadIdx.x;
  const int w = tid >> 6, lane = tid & 63;
  const int l15 = lane & 15, q16 = lane >> 4;
  const int m0 = blockIdx.x * 128, n0 = blockIdx.y * 128;

  const int srow = lane >> 3;
  const int c16s = (lane & 7) ^ srow;
  const short* aSrc0 = A  + (size_t)(m0 + w*32 + srow)*384 + c16s*8;
  const short* bSrc0 = Bw + (size_t)(n0 + w*32 + srow)*384 + c16s*8;

  f32x4 acc[4][4];
#pragma unroll
  for (int mt=0; mt<4; ++mt)
#pragma unroll
    for (int nt=0; nt<4; ++nt) acc[mt][nt] = f32x4{0.f,0.f,0.f,0.f};

  const int wm = w >> 1, wn = w & 1;

#pragma unroll
  for (int j=0; j<4; ++j) {
    gload16(aSrc0 + j*8*384, &lA[0][(w*4 + j)*512]);
    gload16(bSrc0 + j*8*384, &lB[0][(w*4 + j)*512]);
  }
  __syncthreads();

  int cur = 0;
  for (int t = 0; t < 6; ++t) {
    if (t < 5) {
      const short* aS = aSrc0 + (t+1)*64;
      const short* bS = bSrc0 + (t+1)*64;
#pragma unroll
      for (int j=0; j<4; ++j) {
        gload16(aS + j*8*384, &lA[cur^1][(w*4 + j)*512]);
        gload16(bS + j*8*384, &lB[cur^1][(w*4 + j)*512]);
      }
    }
    const short* bufA = lA[cur];
    const short* bufB = lB[cur];
    s16x8 a[4][2], b[4][2];
#pragma unroll
    for (int mt=0; mt<4; ++mt) {
      int ra = wm*64 + mt*16 + l15;
#pragma unroll
      for (int ks=0; ks<2; ++ks) {
        int ca = (ks*4 + q16) ^ (ra & 7);
        a[mt][ks] = *reinterpret_cast<const s16x8*>(&bufA[ra*64 + ca*8]);
      }
    }
#pragma unroll
    for (int nt=0; nt<4; ++nt) {
      int rb = wn*64 + nt*16 + l15;
#pragma unroll
      for (int ks=0; ks<2; ++ks) {
        int cb = (ks*4 + q16) ^ (rb & 7);
        b[nt][ks] = *reinterpret_cast<const s16x8*>(&bufB[rb*64 + cb*8]);
      }
    }
#pragma unroll
    for (int ks=0; ks<2; ++ks)
#pragma unroll
      for (int mt=0; mt<4; ++mt)
#pragma unroll
        for (int nt=0; nt<4; ++nt)
          acc[mt][nt] = MFMA16(a[mt][ks], b[nt][ks], acc[mt][nt]);
    __syncthreads();
    cur ^= 1;
  }

  float* outc = out + (size_t)b0*12544*384;
#pragma unroll
  for (int nt=0; nt<4; ++nt) {
    int ocol = n0 + wn*64 + nt*16 + l15;
    float bp = bias[ocol];
#pragma unroll
    for (int mt=0; mt<4; ++mt) {
      int orow = m0 + wm*64 + mt*16 + q16*4;
#pragma unroll
      for (int r=0; r<4; ++r)
        outc[(size_t)(orow + r)*384 + ocol] = acc[mt][nt][r] + bp;
    }
  }
}

extern "C" void kernel_launch(void* const* d_in, const int* in_sizes, int n_in,
                              void* d_out, int out_size, void* d_ws, size_t ws_size,
                              hipStream_t stream)
{
  (void)in_sizes; (void)n_in; (void)out_size; (void)ws_size;
  const float* x     = (const float*)d_in[0];
  const float* wqkv  = (const float*)d_in[3];
  const float* lng   = (const float*)d_in[4];
  const float* lnb   = (const float*)d_in[5];
  const float* wqk   = (const float*)d_in[6];
  const float* wproj = (const float*)d_in[7];
  const float* bproj = (const float*)d_in[8];
  float* out = (float*)d_out;

  WS W;
  ws_plan((char*)d_ws, &W);

  // full-batch phase
  k0_prep<<<3456, 256, 0, stream>>>(wqkv, wqk, wproj, W.wfrag, W.wqkT, W.wprojT);
  k1_win_attn<<<4096, 256, 0, stream>>>(x, W.wfrag, lng, lnb, W.pv, W.winp);
  k2_pqk<<<dim3(64, 12), 256, 0, stream>>>(W.winp, W.wqkT, W.pq, W.pk);
  k3_pa<<<dim3(192, 4), 256, 0, stream>>>(W.pq, W.pk, W.pa);

  // chunked phase (4 batches each): working set ~85 MB -> L3-resident
  for (int c = 0; c < 4; ++c) {
    const short* pvc = W.pv + (size_t)c*48*256*1568;
    const short* pac = W.pa + (size_t)c*48*256*256;
    k5_po<<<dim3(14, 48), 512, 0, stream>>>(pac, pvc, W.po);
    k6_gemm<<<dim3(392, 3), 256, 0, stream>>>(W.po, W.wprojT, bproj, out, c*4);
  }
}

// Round 18
// 631.508 us; speedup vs baseline: 1.8424x; 1.0320x over previous
//
#include <hip/hip_runtime.h>
#include <hip/hip_bf16.h>
#include <cstdint>

using f32x4 = __attribute__((ext_vector_type(4))) float;
using s16x8 = __attribute__((ext_vector_type(8))) short;
using s16x4 = __attribute__((ext_vector_type(4))) short;

#define MFMA16(A,Bv,Cv) __builtin_amdgcn_mfma_f32_16x16x32_bf16((A),(Bv),(Cv),0,0,0)

__device__ __forceinline__ short f2bf(float f){
  __hip_bfloat16 h = __float2bfloat16(f);           // RNE; compiler fuses pairs to v_cvt_pk_bf16_f32
  union { __hip_bfloat16 h; short s; } u; u.h = h;
  return u.s;
}
__device__ __forceinline__ float bf2f(short s){
  union { unsigned u; float f; } v; v.u = ((unsigned)(unsigned short)s) << 16;
  return v.f;
}
// async global->LDS, 16B per lane; dest = uniform base + lane*16 (HW rule)
__device__ __forceinline__ void gload16(const short* g, short* l){
  __builtin_amdgcn_global_load_lds((const __attribute__((address_space(1))) unsigned int*)g,
                                   (__attribute__((address_space(3))) unsigned int*)l, 16, 0, 0);
}

static constexpr float SCALE_QK = 0.17677669529663687f; // 32^-0.5

// ---- workspace plan: everything full-batch now (po grown to 154 MB) ----
struct WS {
  short *wfrag, *wqkT, *wprojT, *pv, *winp, *pq, *pk, *pa, *po;
};
static size_t ws_plan(char* base, WS* w) {
  size_t o = 0;
  auto take = [&](size_t bytes) -> short* {
    short* p = (short*)(base + o); o += (bytes + 255) & ~(size_t)255; return p;
  };
  short* wfrag = take((size_t)12*12*6*512*2);      // qkv weights in FRAGMENT order (884 KB)
  short* wqkT  = take((size_t)768*384*2);
  short* wproj = take((size_t)384*384*2);
  short* pv    = take((size_t)16*12*256*1568*2);   // 154 MB
  short* winp  = take((size_t)4096*384*2);
  short* pq    = take((size_t)16*12*256*32*2);
  short* pk    = take((size_t)16*12*256*32*2);
  short* pa    = take((size_t)16*12*256*256*2);    // 100 MB
  short* po    = take((size_t)16*12544*384*2);     // 154 MB (full batch)
  if (w) { w->wfrag=wfrag; w->wqkT=wqkT; w->wprojT=wproj; w->pv=pv; w->winp=winp;
           w->pq=pq; w->pk=pk; w->pa=pa; w->po=po; }
  return o;   // ~415 MB
}

// ---------------- k0: weight prep ----------------
// wfrag[hh][ks][half][lane][8]: half 0/1=q lo/hi-16-rows, 2/3=k, 4/5=v; lane=(q16<<4)|l15.
__global__ __launch_bounds__(256) void k0_prep(const float* __restrict__ wqkv,
    const float* __restrict__ wqk, const float* __restrict__ wproj,
    short* __restrict__ wfrag, short* __restrict__ wqkT, short* __restrict__ wprojT)
{
  int i = blockIdx.x * 256 + threadIdx.x;
  if (i < 442368) {
    int j = i & 7, lane = (i >> 3) & 63, half = (i >> 9) % 6, rest = i / 3072;
    int ks = rest % 12, hh = rest / 12;
    int q16 = lane >> 4, l15 = lane & 15;
    int row = (half >> 1)*384 + hh*32 + (half & 1)*16 + l15;
    int col = ks*32 + q16*8 + j;
    wfrag[i] = f2bf(wqkv[(size_t)col*1152 + row]);
    return;
  }
  i -= 442368;
  if (i < 768*384) { int nn = i / 384, kk = i % 384; wqkT[i] = f2bf(wqk[kk*768 + nn]); return; }
  i -= 768*384;
  if (i < 384*384) { int nn = i / 384, kk = i % 384; wprojT[i] = f2bf(wproj[kk*384 + nn]); }
}

// ---------------- k1: fused qkv GEMM + window attention + residual + LN/GELU ----------------
// FUSED q+k+v single K-sweep (R17: 363us, MfmaUtil 32%), unroll 2 for cross-iter load ILP.
// Regs ~96 AGPR + ~120 arch < 256 no-spill cap at (256,2). [R5..R12]: caps SPILL; [R13]: setprio bad.
__global__ __launch_bounds__(256, 2) void k1_win_attn(
    const float* __restrict__ x, const short* __restrict__ wfrag,
    const float* __restrict__ lng, const float* __restrict__ lnb,
    short* __restrict__ pv, short* __restrict__ winpost)
{
  __shared__ short xb[52*392];   // rows 0..49 = x bf16 (ld 392); rows 50..51 alias win[384] floats
  __shared__ float rbuf[8];
  float* win = reinterpret_cast<float*>(&xb[50*392]);

  const int tid = threadIdx.x;
  const int w = tid >> 6;
  const int lane = tid & 63;
  const int l15 = lane & 15, q16 = lane >> 4;
  const int wl = blockIdx.x;             // global window (0..4095)
  const int bl = wl >> 8, n = wl & 255;  // batch, window idx

  {
    const float* xp = x + (size_t)wl * (50*384);
    for (int i = tid; i < 4800; i += 256) {
      float4 v = reinterpret_cast<const float4*>(xp)[i];
      int e = i * 4, t = e / 384, k = e % 384;
      short4 s4; s4.x = f2bf(v.x); s4.y = f2bf(v.y); s4.z = f2bf(v.z); s4.w = f2bf(v.w);
      *reinterpret_cast<short4*>(&xb[t*392 + k]) = s4;
    }
  }
  __syncthreads();

  for (int ih = 0; ih < 3; ++ih) {
    const int hh = w*3 + ih;

    // ---- fused q+k+v pass: Cq = Wq.x^T, Ck = Wk.x^T, Cv = x.Wv^T (shared bx)
    f32x4 cq[2][4], ck[2][4], cv[4][2];
#pragma unroll
    for (int mt=0; mt<2; ++mt)
#pragma unroll
      for (int nt=0; nt<4; ++nt) { cq[mt][nt]=f32x4{0.f,0.f,0.f,0.f}; ck[mt][nt]=f32x4{0.f,0.f,0.f,0.f}; }
#pragma unroll
    for (int sg=0; sg<4; ++sg) { cv[sg][0]=f32x4{0.f,0.f,0.f,0.f}; cv[sg][1]=f32x4{0.f,0.f,0.f,0.f}; }

#pragma unroll 2
    for (int ks = 0; ks < 12; ++ks) {
      const short* wfb = wfrag + ((size_t)(hh*12 + ks)*6)*512 + lane*8;
      s16x8 awq0 = *reinterpret_cast<const s16x8*>(wfb);
      s16x8 awq1 = *reinterpret_cast<const s16x8*>(wfb + 512);
      s16x8 awk0 = *reinterpret_cast<const s16x8*>(wfb + 1024);
      s16x8 awk1 = *reinterpret_cast<const s16x8*>(wfb + 1536);
      s16x8 bwv0 = *reinterpret_cast<const s16x8*>(wfb + 2048);
      s16x8 bwv1 = *reinterpret_cast<const s16x8*>(wfb + 2560);
      s16x8 bx[4];
#pragma unroll
      for (int nt=0; nt<4; ++nt) {
        int rr = nt*16 + l15; rr = rr > 51 ? 51 : rr;   // rows 50/51 garbage (win) — col-isolated
        bx[nt] = *reinterpret_cast<const s16x8*>(&xb[rr*392 + ks*32 + q16*8]);
      }
#pragma unroll
      for (int nt=0; nt<4; ++nt) {
        cq[0][nt] = MFMA16(awq0, bx[nt], cq[0][nt]);
        cq[1][nt] = MFMA16(awq1, bx[nt], cq[1][nt]);
        ck[0][nt] = MFMA16(awk0, bx[nt], ck[0][nt]);
        ck[1][nt] = MFMA16(awk1, bx[nt], ck[1][nt]);
        cv[nt][0] = MFMA16(bx[nt], bwv0, cv[nt][0]);
        cv[nt][1] = MFMA16(bx[nt], bwv1, cv[nt][1]);
      }
    }

    // pack q/k fragments (k-map g1(q16,j) = (j>>2)*16 + q16*4 + (j&3)); fold scale into q
    s16x8 qf[4], kf[4];
#pragma unroll
    for (int nt=0; nt<4; ++nt)
#pragma unroll
      for (int j=0; j<8; ++j) {
        qf[nt][j] = f2bf(cq[j>>2][nt][j&3] * SCALE_QK);  // B-frag q[t=l15][dd=g1]
        kf[nt][j] = f2bf(ck[j>>2][nt][j&3]);             // A-frag k[s=l15][dd=g1] (nt = sti)
      }

    // ---- S^T per t-frag: 4 MFMA + no-max softmax (sum only) + pack unnormalized P
    s16x8 pf[4][2];
    float inv4[4];
#pragma unroll
    for (int nt=0; nt<4; ++nt) {
      f32x4 stc[4];
#pragma unroll
      for (int sti=0; sti<4; ++sti) {
        f32x4 z = {0.f,0.f,0.f,0.f};
        stc[sti] = MFMA16(kf[sti], qf[nt], z);
      }
      float sum = 0.f;
#pragma unroll
      for (int sti=0; sti<4; ++sti)
#pragma unroll
        for (int r=0;r<4;++r) {
          int s = sti*16 + q16*4 + r;
          float p = (s < 50) ? __expf(stc[sti][r]) : 0.f;   // garbage rows predicated off
          stc[sti][r] = p; sum += p;
        }
      sum += __shfl_xor(sum, 16);
      sum += __shfl_xor(sum, 32);
      inv4[nt] = 1.f / sum;
#pragma unroll
      for (int ksp=0; ksp<2; ++ksp)
#pragma unroll
        for (int j=0;j<8;++j)
          pf[nt][ksp][j] = f2bf(stc[ksp*2 + (j>>2)][j&3]);
    }

    // ---- O^T = vT . P^T (K=64 over s); vf guarded s<50  [R15-verified indexing]
    f32x4 ot[2][4];
#pragma unroll
    for (int mt=0; mt<2; ++mt)
#pragma unroll
      for (int nt=0; nt<4; ++nt) ot[mt][nt] = f32x4{0.f,0.f,0.f,0.f};
#pragma unroll
    for (int ksp=0; ksp<2; ++ksp)
#pragma unroll
      for (int mt=0; mt<2; ++mt) {
        s16x8 vf;
#pragma unroll
        for (int j=0;j<8;++j) {
          int s = ksp*32 + (j>>2)*16 + q16*4 + (j&3);
          vf[j] = (s < 50) ? f2bf(cv[ksp*2 + (j>>2)][mt][j&3]) : (short)0;
        }
#pragma unroll
        for (int nt=0; nt<4; ++nt) ot[mt][nt] = MFMA16(vf, pf[nt][ksp], ot[mt][nt]);
      }

    // ---- epilogue: apply deferred inv + residual + scatter
    short* pvb = pv + (((size_t)bl*12 + hh)*256 + n) * 1568;
#pragma unroll
    for (int nt=0; nt<4; ++nt) {
      int t = nt*16 + l15;
      if (t >= 1 && t < 50) {
#pragma unroll
        for (int mt=0; mt<2; ++mt) {
          short4 s4;
#pragma unroll
          for (int r=0;r<4;++r) {
            int dd = mt*16 + q16*4 + r;
            float val = ot[mt][nt][r] * inv4[nt] + bf2f(xb[t*392 + hh*32 + dd]);
            ((short*)&s4)[r] = f2bf(val);
          }
          *reinterpret_cast<short4*>(&pvb[(size_t)(t-1)*32 + mt*16 + q16*4]) = s4;
        }
      } else if (t == 0) {
#pragma unroll
        for (int mt=0; mt<2; ++mt)
#pragma unroll
          for (int r=0;r<4;++r) {
            int dd = mt*16 + q16*4 + r;
            win[hh*32 + dd] = ot[mt][nt][r] * inv4[nt] + bf2f(xb[hh*32 + dd]);
          }
      }
    }
  }

  __syncthreads();
  // ---- LayerNorm + exact GELU on window token
  float s1 = 0.f, s2 = 0.f;
  for (int c = tid; c < 384; c += 256) { float v = win[c]; s1 += v; s2 += v*v; }
#pragma unroll
  for (int o = 32; o >= 1; o >>= 1) { s1 += __shfl_xor(s1, o); s2 += __shfl_xor(s2, o); }
  if (lane == 0) { rbuf[w] = s1; rbuf[4+w] = s2; }
  __syncthreads();
  s1 = rbuf[0] + rbuf[1] + rbuf[2] + rbuf[3];
  s2 = rbuf[4] + rbuf[5] + rbuf[6] + rbuf[7];
  float mean = s1 * (1.f/384.f);
  float var  = s2 * (1.f/384.f) - mean*mean;
  float rstd = rsqrtf(var + 1e-5f);
  for (int c = tid; c < 384; c += 256) {
    float xn = (win[c] - mean) * rstd * lng[c] + lnb[c];
    float ge = 0.5f * xn * (1.f + erff(xn * 0.70710678118654752f));
    winpost[(size_t)wl*384 + c] = f2bf(ge);
  }
}

// ---------------- k2: pq/pk = win_post @ W_qk; SCALE_QK folded into pq (full batch) ----------------
__global__ __launch_bounds__(256) void k2_pqk(const short* __restrict__ winp,
    const short* __restrict__ wqkT, short* __restrict__ pq, short* __restrict__ pk)
{
  const int tid = threadIdx.x;
  const int w = tid >> 6, lane = tid & 63;
  const int l15 = lane & 15, q16 = lane >> 4;
  const int m0 = blockIdx.x * 64, n0 = blockIdx.y * 64;
  f32x4 acc[4];
#pragma unroll
  for (int nt=0; nt<4; ++nt) acc[nt] = f32x4{0.f,0.f,0.f,0.f};
  const int mrow = m0 + w*16 + l15;
  for (int ks2=0; ks2<12; ++ks2) {
    s16x8 a = *reinterpret_cast<const s16x8*>(winp + (size_t)mrow*384 + ks2*32 + q16*8);
#pragma unroll
    for (int nt=0; nt<4; ++nt) {
      s16x8 bf = *reinterpret_cast<const s16x8*>(wqkT + (size_t)(n0 + nt*16 + l15)*384 + ks2*32 + q16*8);
      acc[nt] = MFMA16(a, bf, acc[nt]);
    }
  }
#pragma unroll
  for (int nt=0; nt<4; ++nt)
#pragma unroll
    for (int r=0; r<4; ++r) {
      int m = m0 + w*16 + q16*4 + r;
      int bb = m >> 8, nn = m & 255;
      int c = n0 + nt*16 + l15;
      short* dst = (c >= 384) ? pk : pq;
      float v = acc[nt][r];
      if (c < 384) v *= SCALE_QK;        // fold scale into pq
      int hc = (c >= 384) ? (c - 384) : c;
      int hh = hc >> 5, dd = hc & 31;
      dst[(((size_t)bb*12 + hh)*256 + nn)*32 + dd] = f2bf(v);
    }
}

// ---------------- k3: pa = softmax(pq . pk^T) — 4x row-parallel (grid 192x4) ----------------
__global__ __launch_bounds__(256) void k3_pa(const short* __restrict__ pq,
    const short* __restrict__ pk, short* __restrict__ pa)
{
  __shared__ short ql[64*40];
  __shared__ short kl2[256*40];
  const int tid = threadIdx.x;
  const int w = tid >> 6, lane = tid & 63;
  const int l15 = lane & 15, q16 = lane >> 4;
  const int bh = blockIdx.x, by = blockIdx.y;
  const short* qs = pq + (size_t)bh * 8192;
  const short* ksp = pk + (size_t)bh * 8192;
  {
    int nn = tid >> 2, dd = (tid & 3) * 8;   // ql quarter: rows by*64..+64
    *reinterpret_cast<s16x8*>(&ql[nn*40 + dd]) =
        *reinterpret_cast<const s16x8*>(qs + (size_t)(by*64 + nn)*32 + dd);
  }
  for (int i = tid; i < 1024; i += 256) {
    int nn = i >> 2, dd = (i & 3) * 8;
    *reinterpret_cast<s16x8*>(&kl2[nn*40 + dd]) = *reinterpret_cast<const s16x8*>(ksp + i*8);
  }
  __syncthreads();
  s16x8 a = *reinterpret_cast<const s16x8*>(&ql[(w*16 + l15)*40 + q16*8]);
  f32x4 acc[16];
#pragma unroll
  for (int nt=0; nt<16; ++nt) {
    s16x8 bf = *reinterpret_cast<const s16x8*>(&kl2[(nt*16 + l15)*40 + q16*8]);
    f32x4 z = {0.f,0.f,0.f,0.f};
    acc[nt] = MFMA16(a, bf, z);
  }
#pragma unroll
  for (int r=0; r<4; ++r) {
    float sum = 0.f;
#pragma unroll
    for (int nt=0; nt<16; ++nt) { float p = __expf(acc[nt][r]); acc[nt][r] = p; sum += p; }
    sum += __shfl_xor(sum, 1); sum += __shfl_xor(sum, 2);
    sum += __shfl_xor(sum, 4); sum += __shfl_xor(sum, 8);
    float inv = 1.f / sum;
    int row = by*64 + w*16 + q16*4 + r;
    short* dst = pa + ((size_t)bh*256 + row) * 256;
#pragma unroll
    for (int nt=0; nt<16; ++nt) dst[nt*16 + l15] = f2bf(acc[nt][r] * inv);
  }
}

// ---------------- k5: po = pa @ pv + residual; pv transposed IN-LDS (full batch) ----------------
__global__ __launch_bounds__(512) void k5_po(const short* __restrict__ pa,
    const short* __restrict__ pv, short* __restrict__ po)
{
  __shared__ short vt[112*264];   // 59.1 KB
  const int tid = threadIdx.x;
  const int w = tid >> 6, lane = tid & 63;
  const int l15 = lane & 15, q16 = lane >> 4;
  const int c0 = blockIdx.x * 112;
  const int bh = blockIdx.y;
  const short* pab = pa + (size_t)bh * 256 * 256;
  const short* pvs = pv + (size_t)bh * 256 * 1568;

  // stage pv[0:256][c0:c0+112] -> vt[c_local][n]
  {
    const int n = tid >> 1, half = tid & 1;
    const short* rowp = pvs + (size_t)n*1568 + c0 + half*56;
#pragma unroll
    for (int jj = 0; jj < 7; ++jj) {
      s16x8 v = *reinterpret_cast<const s16x8*>(rowp + jj*8);
#pragma unroll
      for (int j = 0; j < 8; ++j)
        vt[(half*56 + jj*8 + j)*264 + n] = v[j];
    }
  }
  __syncthreads();

  f32x4 acc[2][7];
#pragma unroll
  for (int mt=0; mt<2; ++mt)
#pragma unroll
    for (int nt=0; nt<7; ++nt) acc[mt][nt] = f32x4{0.f,0.f,0.f,0.f};

  const int mrow = w*32;
  for (int ks2 = 0; ks2 < 8; ++ks2) {
    s16x8 a0 = *reinterpret_cast<const s16x8*>(pab + (size_t)(mrow + l15)*256 + ks2*32 + q16*8);
    s16x8 a1 = *reinterpret_cast<const s16x8*>(pab + (size_t)(mrow + 16 + l15)*256 + ks2*32 + q16*8);
#pragma unroll
    for (int nt=0; nt<7; ++nt) {
      s16x8 bf = *reinterpret_cast<const s16x8*>(&vt[(nt*16 + l15)*264 + ks2*32 + q16*8]);
      acc[0][nt] = MFMA16(a0, bf, acc[0][nt]);
      acc[1][nt] = MFMA16(a1, bf, acc[1][nt]);
    }
  }

  const int bl = bh / 12, hh = bh % 12;
#pragma unroll
  for (int nt=0; nt<7; ++nt)
#pragma unroll
    for (int mt=0; mt<2; ++mt)
#pragma unroll
      for (int r=0; r<4; ++r) {
        int nn = mrow + mt*16 + q16*4 + r;
        int cl = nt*16 + l15;
        float val = acc[mt][nt][r] + bf2f(vt[cl*264 + nn]);   // residual from LDS tile
        int col = c0 + cl;
        int wp2 = col >> 5, dd = col & 31;
        int y = (nn >> 4)*7 + wp2/7, xx = (nn & 15)*7 + wp2%7;
        po[((size_t)bl*12544 + y*112 + xx)*384 + hh*32 + dd] = f2bf(val);
      }
}

// ---------------- k6: linear GEMM out = po_lin @ wprojT^T + bias (full batch) ----------------
__global__ __launch_bounds__(256) void k6_gemm(const short* __restrict__ A,
    const short* __restrict__ Bw, const float* __restrict__ bias,
    float* __restrict__ out)
{
  __shared__ short lA[2][128*64];
  __shared__ short lB[2][128*64];
  const int tid = threadIdx.x;
  const int w = tid >> 6, lane = tid & 63;
  const int l15 = lane & 15, q16 = lane >> 4;
  const int m0 = blockIdx.x * 128, n0 = blockIdx.y * 128;

  const int srow = lane >> 3;
  const int c16s = (lane & 7) ^ srow;
  const short* aSrc0 = A  + (size_t)(m0 + w*32 + srow)*384 + c16s*8;
  const short* bSrc0 = Bw + (size_t)(n0 + w*32 + srow)*384 + c16s*8;

  f32x4 acc[4][4];
#pragma unroll
  for (int mt=0; mt<4; ++mt)
#pragma unroll
    for (int nt=0; nt<4; ++nt) acc[mt][nt] = f32x4{0.f,0.f,0.f,0.f};

  const int wm = w >> 1, wn = w & 1;

#pragma unroll
  for (int j=0; j<4; ++j) {
    gload16(aSrc0 + j*8*384, &lA[0][(w*4 + j)*512]);
    gload16(bSrc0 + j*8*384, &lB[0][(w*4 + j)*512]);
  }
  __syncthreads();

  int cur = 0;
  for (int t = 0; t < 6; ++t) {
    if (t < 5) {
      const short* aS = aSrc0 + (t+1)*64;
      const short* bS = bSrc0 + (t+1)*64;
#pragma unroll
      for (int j=0; j<4; ++j) {
        gload16(aS + j*8*384, &lA[cur^1][(w*4 + j)*512]);
        gload16(bS + j*8*384, &lB[cur^1][(w*4 + j)*512]);
      }
    }
    const short* bufA = lA[cur];
    const short* bufB = lB[cur];
    s16x8 a[4][2], b[4][2];
#pragma unroll
    for (int mt=0; mt<4; ++mt) {
      int ra = wm*64 + mt*16 + l15;
#pragma unroll
      for (int ks=0; ks<2; ++ks) {
        int ca = (ks*4 + q16) ^ (ra & 7);
        a[mt][ks] = *reinterpret_cast<const s16x8*>(&bufA[ra*64 + ca*8]);
      }
    }
#pragma unroll
    for (int nt=0; nt<4; ++nt) {
      int rb = wn*64 + nt*16 + l15;
#pragma unroll
      for (int ks=0; ks<2; ++ks) {
        int cb = (ks*4 + q16) ^ (rb & 7);
        b[nt][ks] = *reinterpret_cast<const s16x8*>(&bufB[rb*64 + cb*8]);
      }
    }
#pragma unroll
    for (int ks=0; ks<2; ++ks)
#pragma unroll
      for (int mt=0; mt<4; ++mt)
#pragma unroll
        for (int nt=0; nt<4; ++nt)
          acc[mt][nt] = MFMA16(a[mt][ks], b[nt][ks], acc[mt][nt]);
    __syncthreads();
    cur ^= 1;
  }

#pragma unroll
  for (int nt=0; nt<4; ++nt) {
    int ocol = n0 + wn*64 + nt*16 + l15;
    float bp = bias[ocol];
#pragma unroll
    for (int mt=0; mt<4; ++mt) {
      int orow = m0 + wm*64 + mt*16 + q16*4;
#pragma unroll
      for (int r=0; r<4; ++r)
        out[(size_t)(orow + r)*384 + ocol] = acc[mt][nt][r] + bp;
    }
  }
}

extern "C" void kernel_launch(void* const* d_in, const int* in_sizes, int n_in,
                              void* d_out, int out_size, void* d_ws, size_t ws_size,
                              hipStream_t stream)
{
  (void)in_sizes; (void)n_in; (void)out_size; (void)ws_size;
  const float* x     = (const float*)d_in[0];
  const float* wqkv  = (const float*)d_in[3];
  const float* lng   = (const float*)d_in[4];
  const float* lnb   = (const float*)d_in[5];
  const float* wqk   = (const float*)d_in[6];
  const float* wproj = (const float*)d_in[7];
  const float* bproj = (const float*)d_in[8];
  float* out = (float*)d_out;

  WS W;
  ws_plan((char*)d_ws, &W);

  k0_prep<<<3456, 256, 0, stream>>>(wqkv, wqk, wproj, W.wfrag, W.wqkT, W.wprojT);
  k1_win_attn<<<4096, 256, 0, stream>>>(x, W.wfrag, lng, lnb, W.pv, W.winp);
  k2_pqk<<<dim3(64, 12), 256, 0, stream>>>(W.winp, W.wqkT, W.pq, W.pk);
  k3_pa<<<dim3(192, 4), 256, 0, stream>>>(W.pq, W.pk, W.pa);
  k5_po<<<dim3(14, 192), 512, 0, stream>>>(W.pa, W.pv, W.po);
  k6_gemm<<<dim3(1568, 3), 256, 0, stream>>>(W.po, W.wprojT, bproj, out);
}